// Round 1
// baseline (4649.126 us; speedup 1.0000x reference)
//
#include <hip/hip_runtime.h>
#include <math.h>

#define BLK 256

constexpr int C_Hc = 128;
constexpr int C_INc = 64;
constexpr int Hh = 128;
constexpr int Ww = 128;
constexpr int HWc = Hh * Ww;
constexpr int Bb = 2;
constexpr float EPSV = 1e-5f;

// ---------------------------------------------------------------------------
// Transpose w_df1 [co][ci][3][3] -> wt [ci][tap][co]  (co contiguous)
// ---------------------------------------------------------------------------
__global__ __launch_bounds__(BLK) void k_wt(const float* __restrict__ w1,
                                            float* __restrict__ wt) {
    int idx = blockIdx.x * BLK + threadIdx.x;
    if (idx >= C_Hc * C_Hc * 9) return;
    int co  = idx / (C_Hc * 9);
    int rem = idx - co * (C_Hc * 9);
    int ci  = rem / 9;
    int tap = rem - ci * 9;
    wt[(ci * 9 + tap) * C_Hc + co] = w1[idx];
}

// ---------------------------------------------------------------------------
// conv1x1(w_in) + LayerNorm over channels  (both streams in one grid)
// block = 256 = 4 cgroups x 64 pixel-lanes; tile = 64 consecutive pixels
// ---------------------------------------------------------------------------
__global__ __launch_bounds__(BLK) void k_in_ln(
    const float* __restrict__ xr, const float* __restrict__ xe,
    const float* __restrict__ w_in, const float* __restrict__ lng,
    const float* __restrict__ lnb, float* __restrict__ fr,
    float* __restrict__ fe)
{
    int bid  = blockIdx.x;          // 2 * Bb * 256
    int simg = bid >> 9;
    int rem  = bid & 511;
    int b    = rem >> 8;
    int base = (rem & 255) * 64;
    const float* x  = simg ? xe : xr;
    float*      feat = simg ? fe : fr;
    int lane = threadIdx.x & 63;
    int cg   = threadIdx.x >> 6;

    __shared__ float xs[C_INc][64];
    #pragma unroll
    for (int r = 0; r < 16; ++r) {
        int i = cg * 16 + r;
        xs[i][lane] = x[(b * C_INc + i) * HWc + base + lane];
    }
    __syncthreads();

    float acc[32];
    #pragma unroll
    for (int cc = 0; cc < 32; ++cc) acc[cc] = 0.f;

    for (int i4 = 0; i4 < 16; ++i4) {
        float x0 = xs[i4 * 4 + 0][lane];
        float x1 = xs[i4 * 4 + 1][lane];
        float x2 = xs[i4 * 4 + 2][lane];
        float x3 = xs[i4 * 4 + 3][lane];
        #pragma unroll
        for (int cc = 0; cc < 32; ++cc) {
            float4 wv = *reinterpret_cast<const float4*>(
                &w_in[(cg * 32 + cc) * C_INc + i4 * 4]);
            acc[cc] += wv.x * x0 + wv.y * x1 + wv.z * x2 + wv.w * x3;
        }
    }

    // LayerNorm over 128 channels (4 groups x 32 each)
    float s1 = 0.f, s2 = 0.f;
    #pragma unroll
    for (int cc = 0; cc < 32; ++cc) { s1 += acc[cc]; s2 += acc[cc] * acc[cc]; }
    __shared__ float r1[4][64], r2[4][64];
    r1[cg][lane] = s1; r2[cg][lane] = s2;
    __syncthreads();
    float m   = (r1[0][lane] + r1[1][lane] + r1[2][lane] + r1[3][lane]) * (1.f / C_Hc);
    float ex2 = (r2[0][lane] + r2[1][lane] + r2[2][lane] + r2[3][lane]) * (1.f / C_Hc);
    float rs  = rsqrtf(ex2 - m * m + EPSV);
    #pragma unroll
    for (int cc = 0; cc < 32; ++cc) {
        int c = cg * 32 + cc;
        float y = (acc[cc] - m) * rs * lng[c] + lnb[c];
        feat[(b * C_Hc + c) * HWc + base + lane] = y;
    }
}

// ---------------------------------------------------------------------------
// conv3x3(w_df1) + ReLU, SAME padding.  Tile = 64 consecutive pixels (1 row).
// Input channels staged in LDS in chunks of 32; weights from transposed wt.
// ---------------------------------------------------------------------------
__global__ __launch_bounds__(BLK) void k_conv3(
    const float* __restrict__ feat, const float* __restrict__ wt,
    float* __restrict__ hbuf)
{
    int bid  = blockIdx.x;  // Bb * 256
    int b    = bid >> 8;
    int tile = bid & 255;
    int h0   = tile >> 1;
    int w0   = (tile & 1) << 6;
    int lane = threadIdx.x & 63;
    int cg   = threadIdx.x >> 6;

    __shared__ float xs[32][3][68];
    float acc[32];
    #pragma unroll
    for (int cc = 0; cc < 32; ++cc) acc[cc] = 0.f;

    for (int c0 = 0; c0 < C_Hc; c0 += 32) {
        __syncthreads();
        for (int idx = threadIdx.x; idx < 32 * 3 * 66; idx += BLK) {
            int ci  = idx / 198;
            int rem = idx - ci * 198;
            int r   = rem / 66;
            int col = rem - r * 66;
            int gh  = h0 + r - 1;
            int gw  = w0 + col - 1;
            float v = 0.f;
            if ((unsigned)gh < (unsigned)Hh && (unsigned)gw < (unsigned)Ww)
                v = feat[(b * C_Hc + c0 + ci) * HWc + gh * Ww + gw];
            xs[ci][r][col] = v;
        }
        __syncthreads();
        for (int ci = 0; ci < 32; ++ci) {
            float xv[9];
            #pragma unroll
            for (int ki = 0; ki < 3; ++ki)
                #pragma unroll
                for (int kj = 0; kj < 3; ++kj)
                    xv[ki * 3 + kj] = xs[ci][ki][lane + kj];
            const float* wp = &wt[((c0 + ci) * 9) * C_Hc + cg * 32];
            #pragma unroll
            for (int tap = 0; tap < 9; ++tap) {
                #pragma unroll
                for (int q = 0; q < 8; ++q) {
                    float4 wv = *reinterpret_cast<const float4*>(
                        &wp[tap * C_Hc + q * 4]);
                    acc[q * 4 + 0] += wv.x * xv[tap];
                    acc[q * 4 + 1] += wv.y * xv[tap];
                    acc[q * 4 + 2] += wv.z * xv[tap];
                    acc[q * 4 + 3] += wv.w * xv[tap];
                }
            }
        }
    }
    #pragma unroll
    for (int cc = 0; cc < 32; ++cc) {
        float v = acc[cc];
        hbuf[(b * C_Hc + cg * 32 + cc) * HWc + h0 * Ww + w0 + lane] =
            v > 0.f ? v : 0.f;
    }
}

// ---------------------------------------------------------------------------
// Fused: filt = w_df2 @ h  (per-pixel 3200x128 matvec) immediately consumed by
// the 25-tap dynamic-filter apply.  Never materializes the 419 MB filter.
// ---------------------------------------------------------------------------
__global__ __launch_bounds__(BLK) void k_dfapply(
    const float* __restrict__ hbuf, const float* __restrict__ feat,
    const float* __restrict__ w2, float* __restrict__ enh)
{
    int bid  = blockIdx.x;  // Bb * 256
    int b    = bid >> 8;
    int tile = bid & 255;
    int h0   = tile >> 1;
    int w0   = (tile & 1) << 6;
    int base = h0 * Ww + w0;
    int lane = threadIdx.x & 63;
    int cg   = threadIdx.x >> 6;

    __shared__ float hs[C_Hc][64];
    #pragma unroll
    for (int r = 0; r < 32; ++r) {
        int j = cg * 32 + r;
        hs[j][lane] = hbuf[(b * C_Hc + j) * HWc + base + lane];
    }
    __syncthreads();

    float oacc[32];
    #pragma unroll
    for (int cc = 0; cc < 32; ++cc) oacc[cc] = 0.f;

    for (int k = 0; k < 25; ++k) {
        int dh = k / 5 - 2;
        int dw = k % 5 - 2;
        float facc[32];
        #pragma unroll
        for (int cc = 0; cc < 32; ++cc) facc[cc] = 0.f;
        for (int j4 = 0; j4 < 32; ++j4) {
            float x0 = hs[j4 * 4 + 0][lane];
            float x1 = hs[j4 * 4 + 1][lane];
            float x2 = hs[j4 * 4 + 2][lane];
            float x3 = hs[j4 * 4 + 3][lane];
            #pragma unroll
            for (int cc = 0; cc < 32; ++cc) {
                int c = cg * 32 + cc;
                float4 wv = *reinterpret_cast<const float4*>(
                    &w2[((c * 25 + k) * C_Hc) + j4 * 4]);
                facc[cc] += wv.x * x0 + wv.y * x1 + wv.z * x2 + wv.w * x3;
            }
        }
        int gh = h0 + dh;
        int gw0 = w0 + lane + dw;
        bool ok = ((unsigned)gh < (unsigned)Hh) && ((unsigned)gw0 < (unsigned)Ww);
        #pragma unroll
        for (int cc = 0; cc < 32; ++cc) {
            int c = cg * 32 + cc;
            float fv = ok ? feat[(b * C_Hc + c) * HWc + gh * Ww + gw0] : 0.f;
            oacc[cc] += facc[cc] * fv;
        }
    }
    #pragma unroll
    for (int cc = 0; cc < 32; ++cc)
        enh[(b * C_Hc + cg * 32 + cc) * HWc + base + lane] = oacc[cc];
}

// ---------------------------------------------------------------------------
// Tail: sp = conv1x1(w_sp, event_enh); fused = rgb_enh*(1+sigmoid(sp))+rgb_feat
// -> LayerNorm -> conv1x1(w_out) -> d_out
// ---------------------------------------------------------------------------
__global__ __launch_bounds__(BLK) void k_final(
    const float* __restrict__ enh_r, const float* __restrict__ enh_e,
    const float* __restrict__ featr, const float* __restrict__ w_sp,
    const float* __restrict__ lng, const float* __restrict__ lnb,
    const float* __restrict__ w_out, float* __restrict__ out)
{
    int bid  = blockIdx.x;  // Bb * 256
    int b    = bid >> 8;
    int base = (bid & 255) * 64;
    int lane = threadIdx.x & 63;
    int cg   = threadIdx.x >> 6;

    __shared__ float es[C_Hc][64];
    #pragma unroll
    for (int r = 0; r < 32; ++r) {
        int j = cg * 32 + r;
        es[j][lane] = enh_e[(b * C_Hc + j) * HWc + base + lane];
    }
    __syncthreads();

    float sacc[32];
    #pragma unroll
    for (int cc = 0; cc < 32; ++cc) sacc[cc] = 0.f;
    for (int j4 = 0; j4 < 32; ++j4) {
        float x0 = es[j4 * 4 + 0][lane];
        float x1 = es[j4 * 4 + 1][lane];
        float x2 = es[j4 * 4 + 2][lane];
        float x3 = es[j4 * 4 + 3][lane];
        #pragma unroll
        for (int cc = 0; cc < 32; ++cc) {
            float4 wv = *reinterpret_cast<const float4*>(
                &w_sp[(cg * 32 + cc) * C_Hc + j4 * 4]);
            sacc[cc] += wv.x * x0 + wv.y * x1 + wv.z * x2 + wv.w * x3;
        }
    }

    float fu[32];
    float s1 = 0.f, s2 = 0.f;
    #pragma unroll
    for (int cc = 0; cc < 32; ++cc) {
        int c = cg * 32 + cc;
        long long off = (long long)(b * C_Hc + c) * HWc + base + lane;
        float re = enh_r[off];
        float rf = featr[off];
        float sg = 1.f / (1.f + __expf(-sacc[cc]));
        float f  = re + re * sg + rf;
        fu[cc] = f;
        s1 += f; s2 += f * f;
    }
    __shared__ float r1[4][64], r2[4][64];
    r1[cg][lane] = s1; r2[cg][lane] = s2;
    __syncthreads();
    float m   = (r1[0][lane] + r1[1][lane] + r1[2][lane] + r1[3][lane]) * (1.f / C_Hc);
    float ex2 = (r2[0][lane] + r2[1][lane] + r2[2][lane] + r2[3][lane]) * (1.f / C_Hc);
    float rs  = rsqrtf(ex2 - m * m + EPSV);

    #pragma unroll
    for (int cc = 0; cc < 32; ++cc) {
        int c = cg * 32 + cc;
        es[c][lane] = (fu[cc] - m) * rs * lng[c] + lnb[c];
    }
    __syncthreads();

    float oacc[16];
    #pragma unroll
    for (int oo = 0; oo < 16; ++oo) oacc[oo] = 0.f;
    for (int j4 = 0; j4 < 32; ++j4) {
        float x0 = es[j4 * 4 + 0][lane];
        float x1 = es[j4 * 4 + 1][lane];
        float x2 = es[j4 * 4 + 2][lane];
        float x3 = es[j4 * 4 + 3][lane];
        #pragma unroll
        for (int oo = 0; oo < 16; ++oo) {
            int o = cg * 16 + oo;
            float4 wv = *reinterpret_cast<const float4*>(
                &w_out[o * C_Hc + j4 * 4]);
            oacc[oo] += wv.x * x0 + wv.y * x1 + wv.z * x2 + wv.w * x3;
        }
    }
    #pragma unroll
    for (int oo = 0; oo < 16; ++oo)
        out[(b * C_INc + cg * 16 + oo) * HWc + base + lane] = oacc[oo];
}

// ---------------------------------------------------------------------------
extern "C" void kernel_launch(void* const* d_in, const int* in_sizes, int n_in,
                              void* d_out, int out_size, void* d_ws, size_t ws_size,
                              hipStream_t stream)
{
    const float* rgb  = (const float*)d_in[0];
    const float* evt  = (const float*)d_in[1];
    const float* w_in = (const float*)d_in[2];
    const float* lng  = (const float*)d_in[3];
    const float* lnb  = (const float*)d_in[4];
    const float* w1   = (const float*)d_in[5];
    const float* w2   = (const float*)d_in[6];
    const float* wsp  = (const float*)d_in[7];
    const float* wout = (const float*)d_in[8];
    float* out = (float*)d_out;

    float* ws = (float*)d_ws;
    const long long N1f = (long long)Bb * C_Hc * HWc;  // 4,194,304 floats
    float* featr = ws;
    float* feate = ws + N1f;
    float* hbuf  = ws + 2 * N1f;
    float* enhr  = ws + 3 * N1f;
    float* enhe  = ws + 4 * N1f;
    float* wt    = ws + 5 * N1f;  // 147456 floats

    k_wt<<<(C_Hc * C_Hc * 9 + BLK - 1) / BLK, BLK, 0, stream>>>(w1, wt);
    k_in_ln<<<2 * Bb * 256, BLK, 0, stream>>>(rgb, evt, w_in, lng, lnb, featr, feate);

    k_conv3<<<Bb * 256, BLK, 0, stream>>>(featr, wt, hbuf);
    k_dfapply<<<Bb * 256, BLK, 0, stream>>>(hbuf, featr, w2, enhr);

    k_conv3<<<Bb * 256, BLK, 0, stream>>>(feate, wt, hbuf);
    k_dfapply<<<Bb * 256, BLK, 0, stream>>>(hbuf, feate, w2, enhe);

    k_final<<<Bb * 256, BLK, 0, stream>>>(enhr, enhe, featr, wsp, lng, lnb, wout, out);
}

// Round 2
// 565.208 us; speedup vs baseline: 8.2255x; 8.2255x over previous
//
#include <hip/hip_runtime.h>
#include <math.h>

#define BLK 256

typedef unsigned short ushort;
typedef unsigned int uint;
typedef __attribute__((ext_vector_type(8))) short short8;
typedef __attribute__((ext_vector_type(4))) float f32x4;

constexpr int C_Hc = 128;
constexpr int C_INc = 64;
constexpr int Hh = 128;
constexpr int Ww = 128;
constexpr int HWc = Hh * Ww;   // 16384
constexpr int Bb = 2;
constexpr float EPSV = 1e-5f;

__device__ __forceinline__ float bf2f(ushort u) {
    union { uint u32; float f; } v; v.u32 = (uint)u << 16; return v.f;
}
__device__ __forceinline__ ushort f2bf(float x) {
    union { float f; uint u; } v; v.f = x;
    uint r = (v.u + 0x7FFFu + ((v.u >> 16) & 1u)) >> 16;
    return (ushort)r;
}

// ---------------------------------------------------------------------------
// Weight prep: wA[tap][co][ci] bf16 from w1[co][ci][3][3];
//              w2b[k][c][ci] bf16 from w2[c*25+k][ci]
// ---------------------------------------------------------------------------
__global__ __launch_bounds__(BLK) void k_prep(const float* __restrict__ w1,
                                              const float* __restrict__ w2,
                                              ushort* __restrict__ wA,
                                              ushort* __restrict__ w2b) {
    int idx = blockIdx.x * BLK + threadIdx.x;
    if (idx < 9 * 128 * 128) {
        int tap = idx >> 14, rem = idx & 16383;
        int co = rem >> 7, ci = rem & 127;
        wA[idx] = f2bf(w1[((co << 7) + ci) * 9 + tap]);
    } else {
        int i2 = idx - 9 * 128 * 128;
        if (i2 < 25 * 128 * 128) {
            int k = i2 >> 14, rem = i2 & 16383;
            int c = rem >> 7, ci = rem & 127;
            w2b[i2] = f2bf(w2[(c * 25 + k) * 128 + ci]);
        }
    }
}

// ---------------------------------------------------------------------------
// conv1x1(w_in) + LayerNorm over channels; writes featr fp32 (rgb only, for
// the tail) and featT bf16 NHWC (both streams, feeds the MFMA kernels).
// ---------------------------------------------------------------------------
__global__ __launch_bounds__(BLK) void k_in_ln(
    const float* __restrict__ xr, const float* __restrict__ xe,
    const float* __restrict__ w_in, const float* __restrict__ lng,
    const float* __restrict__ lnb, float* __restrict__ featr,
    ushort* __restrict__ fTr, ushort* __restrict__ fTe)
{
    int bid  = blockIdx.x;          // 2 * Bb * 256
    int simg = bid >> 9;
    int rem  = bid & 511;
    int b    = rem >> 8;
    int base = (rem & 255) * 64;
    const float* x = simg ? xe : xr;
    ushort* fT = simg ? fTe : fTr;
    int lane = threadIdx.x & 63;
    int cg   = threadIdx.x >> 6;

    __shared__ float xs[C_INc][64];
    #pragma unroll
    for (int r = 0; r < 16; ++r) {
        int i = cg * 16 + r;
        xs[i][lane] = x[(b * C_INc + i) * HWc + base + lane];
    }
    __syncthreads();

    float acc[32];
    #pragma unroll
    for (int cc = 0; cc < 32; ++cc) acc[cc] = 0.f;

    for (int i4 = 0; i4 < 16; ++i4) {
        float x0 = xs[i4 * 4 + 0][lane];
        float x1 = xs[i4 * 4 + 1][lane];
        float x2 = xs[i4 * 4 + 2][lane];
        float x3 = xs[i4 * 4 + 3][lane];
        #pragma unroll
        for (int cc = 0; cc < 32; ++cc) {
            float4 wv = *reinterpret_cast<const float4*>(
                &w_in[(cg * 32 + cc) * C_INc + i4 * 4]);
            acc[cc] += wv.x * x0 + wv.y * x1 + wv.z * x2 + wv.w * x3;
        }
    }

    float s1 = 0.f, s2 = 0.f;
    #pragma unroll
    for (int cc = 0; cc < 32; ++cc) { s1 += acc[cc]; s2 += acc[cc] * acc[cc]; }
    __shared__ float r1[4][64], r2[4][64];
    r1[cg][lane] = s1; r2[cg][lane] = s2;
    __syncthreads();
    float m   = (r1[0][lane] + r1[1][lane] + r1[2][lane] + r1[3][lane]) * (1.f / C_Hc);
    float ex2 = (r2[0][lane] + r2[1][lane] + r2[2][lane] + r2[3][lane]) * (1.f / C_Hc);
    float rs  = rsqrtf(ex2 - m * m + EPSV);

    long long tbase = ((long long)((b << 14) + base + lane) << 7) + cg * 32;
    #pragma unroll
    for (int cc = 0; cc < 32; cc += 2) {
        int c0 = cg * 32 + cc;
        float y0 = (acc[cc]     - m) * rs * lng[c0]     + lnb[c0];
        float y1 = (acc[cc + 1] - m) * rs * lng[c0 + 1] + lnb[c0 + 1];
        if (!simg) {
            featr[(long long)(b * C_Hc + c0) * HWc + base + lane]     = y0;
            featr[(long long)(b * C_Hc + c0 + 1) * HWc + base + lane] = y1;
        }
        *reinterpret_cast<uint*>(&fT[tbase + cc]) =
            (uint)f2bf(y0) | ((uint)f2bf(y1) << 16);
    }
}

// ---------------------------------------------------------------------------
// conv3x3 + ReLU via 9 shifted MFMA GEMMs.  Block tile: [co=128] x [px=64]
// (one image row segment).  LDS: 3 x 66 x 128ci bf16, XOR-swizzled.
// Output hT bf16 NHWC.
// ---------------------------------------------------------------------------
__global__ __launch_bounds__(BLK) void k_conv3(
    const ushort* __restrict__ fTr, const ushort* __restrict__ fTe,
    const ushort* __restrict__ wA,
    ushort* __restrict__ hTr, ushort* __restrict__ hTe)
{
    int bid = blockIdx.x;           // 2 * Bb * 256
    int s = bid >> 9, r = bid & 511;
    int b = r >> 8, t = r & 255;
    int h0 = t >> 1, w0 = (t & 1) << 6;
    const ushort* fT = s ? fTe : fTr;
    ushort* hT = s ? hTe : hTr;
    int tid = threadIdx.x, lane = tid & 63;
    int wv = tid >> 6, lpx = lane & 15, lk = lane >> 4;

    __shared__ ushort lds[3 * 66 * 128];

    for (int i = tid; i < 3 * 66 * 16; i += BLK) {
        int chunk = i & 15, cr = i >> 4;
        int col = cr % 66, row = cr / 66;
        int gh = h0 + row - 1, gw = w0 + col - 1;
        uint4 v = make_uint4(0, 0, 0, 0);
        if ((unsigned)gh < 128u && (unsigned)gw < 128u)
            v = *reinterpret_cast<const uint4*>(
                &fT[(((long long)(b << 14) + (gh << 7) + gw) << 7) + (chunk << 3)]);
        int sw = chunk ^ (col & 7);
        *reinterpret_cast<uint4*>(&lds[((row * 66 + col) * 16 + sw) << 3]) = v;
    }
    __syncthreads();

    f32x4 acc[8];
    #pragma unroll
    for (int f = 0; f < 8; ++f) acc[f] = f32x4{0.f, 0.f, 0.f, 0.f};

    for (int tap = 0; tap < 9; ++tap) {
        int ki = tap / 3, kj = tap - ki * 3;
        int col = wv * 16 + lpx + kj;       // 0..65
        short8 bq[4];
        #pragma unroll
        for (int q = 0; q < 4; ++q) {
            int sw = (q * 4 + lk) ^ (col & 7);
            bq[q] = *reinterpret_cast<const short8*>(
                &lds[((ki * 66 + col) * 16 + sw) << 3]);
        }
        #pragma unroll
        for (int q = 0; q < 4; ++q)
            #pragma unroll
            for (int f = 0; f < 8; ++f) {
                short8 a = *reinterpret_cast<const short8*>(
                    &wA[(((tap << 7) + f * 16 + lpx) << 7) + (q << 5) + (lk << 3)]);
                acc[f] = __builtin_amdgcn_mfma_f32_16x16x32_bf16(a, bq[q], acc[f], 0, 0, 0);
            }
    }

    int px = w0 + wv * 16 + lpx;
    long long obase = ((long long)(b << 14) + (h0 << 7) + px) << 7;
    #pragma unroll
    for (int f = 0; f < 8; ++f) {
        int c = f * 16 + lk * 4;
        float v0 = fmaxf(acc[f][0], 0.f), v1 = fmaxf(acc[f][1], 0.f);
        float v2 = fmaxf(acc[f][2], 0.f), v3 = fmaxf(acc[f][3], 0.f);
        *reinterpret_cast<uint*>(&hT[obase + c])     = (uint)f2bf(v0) | ((uint)f2bf(v1) << 16);
        *reinterpret_cast<uint*>(&hT[obase + c + 2]) = (uint)f2bf(v2) | ((uint)f2bf(v3) << 16);
    }
}

// ---------------------------------------------------------------------------
// Fused dynamic-filter: per tap k, stage w2b[k] (128x128 bf16) in swizzled
// LDS, MFMA -> filt tile [128 c x 64 px], immediately MAC against shifted
// featT into fp32 accumulators.  Output enh bf16 NCHW.
// ---------------------------------------------------------------------------
__global__ __launch_bounds__(BLK) void k_dfapply(
    const ushort* __restrict__ hTr, const ushort* __restrict__ hTe,
    const ushort* __restrict__ fTr, const ushort* __restrict__ fTe,
    const ushort* __restrict__ w2b,
    ushort* __restrict__ enhr, ushort* __restrict__ enhe)
{
    int bid = blockIdx.x;           // 2 * Bb * 256
    int s = bid >> 9, rr = bid & 511;
    int b = rr >> 8, t = rr & 255;
    int h0 = t >> 1, w0 = (t & 1) << 6;
    const ushort* hT = s ? hTe : hTr;
    const ushort* fT = s ? fTe : fTr;
    ushort* enh = s ? enhe : enhr;
    int tid = threadIdx.x, lane = tid & 63;
    int wv = tid >> 6, lpx = lane & 15, lk = lane >> 4;

    __shared__ ushort hs[64 * 128];
    __shared__ ushort wk[128 * 128];

    for (int i = tid; i < 64 * 16; i += BLK) {
        int chunk = i & 15, px = i >> 4;
        uint4 v = *reinterpret_cast<const uint4*>(
            &hT[(((long long)(b << 14) + (h0 << 7) + w0 + px) << 7) + (chunk << 3)]);
        int sw = chunk ^ (px & 7);
        *reinterpret_cast<uint4*>(&hs[(px * 16 + sw) << 3]) = v;
    }
    __syncthreads();

    int col = wv * 16 + lpx;        // output px within tile, 0..63
    short8 bq[4];
    #pragma unroll
    for (int q = 0; q < 4; ++q) {
        int sw = (q * 4 + lk) ^ (col & 7);
        bq[q] = *reinterpret_cast<const short8*>(&hs[(col * 16 + sw) << 3]);
    }

    f32x4 osum[8];
    #pragma unroll
    for (int f = 0; f < 8; ++f) osum[f] = f32x4{0.f, 0.f, 0.f, 0.f};

    for (int k = 0; k < 25; ++k) {
        __syncthreads();            // previous tap's wk reads done
        for (int i = tid; i < 128 * 16; i += BLK) {
            int chunk = i & 15, co = i >> 4;
            uint4 v = *reinterpret_cast<const uint4*>(
                &w2b[(((k << 7) + co) << 7) + (chunk << 3)]);
            int sw = chunk ^ (co & 7);
            *reinterpret_cast<uint4*>(&wk[(co * 16 + sw) << 3]) = v;
        }
        __syncthreads();

        f32x4 fac[8];
        #pragma unroll
        for (int f = 0; f < 8; ++f) fac[f] = f32x4{0.f, 0.f, 0.f, 0.f};
        #pragma unroll
        for (int q = 0; q < 4; ++q) {
            #pragma unroll
            for (int f = 0; f < 8; ++f) {
                int sw = (q * 4 + lk) ^ (lpx & 7);
                short8 a = *reinterpret_cast<const short8*>(
                    &wk[((f * 16 + lpx) * 16 + sw) << 3]);
                fac[f] = __builtin_amdgcn_mfma_f32_16x16x32_bf16(a, bq[q], fac[f], 0, 0, 0);
            }
        }

        int dh = k / 5 - 2, dw = k - (k / 5) * 5 - 2;
        int gh = h0 + dh, gw = w0 + col + dw;
        bool ok = ((unsigned)gh < 128u) && ((unsigned)gw < 128u);
        const ushort* fp = &fT[((long long)(b << 14) + (gh << 7) + gw) << 7];
        #pragma unroll
        for (int f = 0; f < 8; ++f) {
            int c = f * 16 + lk * 4;
            float f0 = 0.f, f1 = 0.f, f2 = 0.f, f3 = 0.f;
            if (ok) {
                uint2 fv = *reinterpret_cast<const uint2*>(&fp[c]);
                f0 = bf2f((ushort)(fv.x & 0xffff)); f1 = bf2f((ushort)(fv.x >> 16));
                f2 = bf2f((ushort)(fv.y & 0xffff)); f3 = bf2f((ushort)(fv.y >> 16));
            }
            osum[f][0] += fac[f][0] * f0; osum[f][1] += fac[f][1] * f1;
            osum[f][2] += fac[f][2] * f2; osum[f][3] += fac[f][3] * f3;
        }
    }

    #pragma unroll
    for (int f = 0; f < 8; ++f) {
        int c = f * 16 + lk * 4;
        #pragma unroll
        for (int rix = 0; rix < 4; ++rix)
            enh[(long long)(b * C_Hc + c + rix) * HWc + (h0 << 7) + w0 + col] =
                f2bf(osum[f][rix]);
    }
}

// ---------------------------------------------------------------------------
// Tail: sp conv + sigmoid gate + fuse + LN + out conv.  fp32.
// ---------------------------------------------------------------------------
__global__ __launch_bounds__(BLK) void k_final(
    const ushort* __restrict__ enh_r, const ushort* __restrict__ enh_e,
    const float* __restrict__ featr, const float* __restrict__ w_sp,
    const float* __restrict__ lng, const float* __restrict__ lnb,
    const float* __restrict__ w_out, float* __restrict__ out)
{
    int bid  = blockIdx.x;  // Bb * 256
    int b    = bid >> 8;
    int base = (bid & 255) * 64;
    int lane = threadIdx.x & 63;
    int cg   = threadIdx.x >> 6;

    __shared__ float es[C_Hc][64];
    #pragma unroll
    for (int r = 0; r < 32; ++r) {
        int j = cg * 32 + r;
        es[j][lane] = bf2f(enh_e[(long long)(b * C_Hc + j) * HWc + base + lane]);
    }
    __syncthreads();

    float sacc[32];
    #pragma unroll
    for (int cc = 0; cc < 32; ++cc) sacc[cc] = 0.f;
    for (int j4 = 0; j4 < 32; ++j4) {
        float x0 = es[j4 * 4 + 0][lane];
        float x1 = es[j4 * 4 + 1][lane];
        float x2 = es[j4 * 4 + 2][lane];
        float x3 = es[j4 * 4 + 3][lane];
        #pragma unroll
        for (int cc = 0; cc < 32; ++cc) {
            float4 wv = *reinterpret_cast<const float4*>(
                &w_sp[(cg * 32 + cc) * C_Hc + j4 * 4]);
            sacc[cc] += wv.x * x0 + wv.y * x1 + wv.z * x2 + wv.w * x3;
        }
    }

    float fu[32];
    float s1 = 0.f, s2 = 0.f;
    #pragma unroll
    for (int cc = 0; cc < 32; ++cc) {
        int c = cg * 32 + cc;
        long long off = (long long)(b * C_Hc + c) * HWc + base + lane;
        float re = bf2f(enh_r[off]);
        float rf = featr[off];
        float sg = 1.f / (1.f + __expf(-sacc[cc]));
        float f  = re + re * sg + rf;
        fu[cc] = f;
        s1 += f; s2 += f * f;
    }
    __shared__ float r1[4][64], r2[4][64];
    r1[cg][lane] = s1; r2[cg][lane] = s2;
    __syncthreads();
    float m   = (r1[0][lane] + r1[1][lane] + r1[2][lane] + r1[3][lane]) * (1.f / C_Hc);
    float ex2 = (r2[0][lane] + r2[1][lane] + r2[2][lane] + r2[3][lane]) * (1.f / C_Hc);
    float rs  = rsqrtf(ex2 - m * m + EPSV);

    #pragma unroll
    for (int cc = 0; cc < 32; ++cc) {
        int c = cg * 32 + cc;
        es[c][lane] = (fu[cc] - m) * rs * lng[c] + lnb[c];
    }
    __syncthreads();

    float oacc[16];
    #pragma unroll
    for (int oo = 0; oo < 16; ++oo) oacc[oo] = 0.f;
    for (int j4 = 0; j4 < 32; ++j4) {
        float x0 = es[j4 * 4 + 0][lane];
        float x1 = es[j4 * 4 + 1][lane];
        float x2 = es[j4 * 4 + 2][lane];
        float x3 = es[j4 * 4 + 3][lane];
        #pragma unroll
        for (int oo = 0; oo < 16; ++oo) {
            int o = cg * 16 + oo;
            float4 wv = *reinterpret_cast<const float4*>(
                &w_out[o * C_Hc + j4 * 4]);
            oacc[oo] += wv.x * x0 + wv.y * x1 + wv.z * x2 + wv.w * x3;
        }
    }
    #pragma unroll
    for (int oo = 0; oo < 16; ++oo)
        out[(long long)(b * C_INc + cg * 16 + oo) * HWc + base + lane] = oacc[oo];
}

// ---------------------------------------------------------------------------
extern "C" void kernel_launch(void* const* d_in, const int* in_sizes, int n_in,
                              void* d_out, int out_size, void* d_ws, size_t ws_size,
                              hipStream_t stream)
{
    const float* rgb  = (const float*)d_in[0];
    const float* evt  = (const float*)d_in[1];
    const float* w_in = (const float*)d_in[2];
    const float* lng  = (const float*)d_in[3];
    const float* lnb  = (const float*)d_in[4];
    const float* w1   = (const float*)d_in[5];
    const float* w2   = (const float*)d_in[6];
    const float* wsp  = (const float*)d_in[7];
    const float* wout = (const float*)d_in[8];
    float* out = (float*)d_out;

    float* ws = (float*)d_ws;
    float*  featr = ws;                              // 4,194,304 f
    ushort* fTr   = (ushort*)(ws + 4194304);         // 2,097,152 f
    ushort* fTe   = (ushort*)(ws + 6291456);
    ushort* hTr   = (ushort*)(ws + 8388608);
    ushort* hTe   = (ushort*)(ws + 10485760);
    ushort* enhr  = (ushort*)(ws + 12582912);
    ushort* enhe  = (ushort*)(ws + 14680064);
    ushort* wA    = (ushort*)(ws + 16777216);        // 73,728 f
    ushort* w2b   = (ushort*)(ws + 16850944);        // 204,800 f

    k_prep<<<2176, BLK, 0, stream>>>(w1, w2, wA, w2b);
    k_in_ln<<<2 * Bb * 256, BLK, 0, stream>>>(rgb, evt, w_in, lng, lnb,
                                              featr, fTr, fTe);
    k_conv3<<<2 * Bb * 256, BLK, 0, stream>>>(fTr, fTe, wA, hTr, hTe);
    k_dfapply<<<2 * Bb * 256, BLK, 0, stream>>>(hTr, hTe, fTr, fTe, w2b,
                                                enhr, enhe);
    k_final<<<Bb * 256, BLK, 0, stream>>>(enhr, enhe, featr, wsp, lng, lnb,
                                          wout, out);
}

// Round 3
// 371.331 us; speedup vs baseline: 12.5202x; 1.5221x over previous
//
#include <hip/hip_runtime.h>
#include <math.h>

#define BLK 256

typedef unsigned short ushort;
typedef unsigned int uint;
typedef __attribute__((ext_vector_type(8))) short short8;
typedef __attribute__((ext_vector_type(4))) float f32x4;

constexpr int C_Hc = 128;
constexpr int C_INc = 64;
constexpr int Hh = 128;
constexpr int Ww = 128;
constexpr int HWc = Hh * Ww;   // 16384
constexpr int Bb = 2;
constexpr float EPSV = 1e-5f;

__device__ __forceinline__ float bf2f(ushort u) {
    union { uint u32; float f; } v; v.u32 = (uint)u << 16; return v.f;
}
__device__ __forceinline__ ushort f2bf(float x) {
    union { float f; uint u; } v; v.f = x;
    uint r = (v.u + 0x7FFFu + ((v.u >> 16) & 1u)) >> 16;
    return (ushort)r;
}
__device__ __forceinline__ void gload16(const ushort* g, ushort* l) {
    __builtin_amdgcn_global_load_lds(
        (const __attribute__((address_space(1))) void*)g,
        (__attribute__((address_space(3))) void*)l, 16, 0, 0);
}

// ---------------------------------------------------------------------------
// Weight prep: wA[tap][co][ci] bf16 ; w2b[k][c][ci] bf16
// ---------------------------------------------------------------------------
__global__ __launch_bounds__(BLK) void k_prep(const float* __restrict__ w1,
                                              const float* __restrict__ w2,
                                              ushort* __restrict__ wA,
                                              ushort* __restrict__ w2b) {
    int idx = blockIdx.x * BLK + threadIdx.x;
    if (idx < 9 * 128 * 128) {
        int tap = idx >> 14, rem = idx & 16383;
        int co = rem >> 7, ci = rem & 127;
        wA[idx] = f2bf(w1[((co << 7) + ci) * 9 + tap]);
    } else {
        int i2 = idx - 9 * 128 * 128;
        if (i2 < 25 * 128 * 128) {
            int k = i2 >> 14, rem = i2 & 16383;
            int c = rem >> 7, ci = rem & 127;
            w2b[i2] = f2bf(w2[(c * 25 + k) * 128 + ci]);
        }
    }
}

// ---------------------------------------------------------------------------
// conv1x1(w_in) + LayerNorm; featr fp32 (rgb only) + featT bf16 NHWC.
// ---------------------------------------------------------------------------
__global__ __launch_bounds__(BLK) void k_in_ln(
    const float* __restrict__ xr, const float* __restrict__ xe,
    const float* __restrict__ w_in, const float* __restrict__ lng,
    const float* __restrict__ lnb, float* __restrict__ featr,
    ushort* __restrict__ fTr, ushort* __restrict__ fTe)
{
    int bid  = blockIdx.x;          // 2 * Bb * 256
    int simg = bid >> 9;
    int rem  = bid & 511;
    int b    = rem >> 8;
    int base = (rem & 255) * 64;
    const float* x = simg ? xe : xr;
    ushort* fT = simg ? fTe : fTr;
    int lane = threadIdx.x & 63;
    int cg   = threadIdx.x >> 6;

    __shared__ float xs[C_INc][64];
    #pragma unroll
    for (int r = 0; r < 16; ++r) {
        int i = cg * 16 + r;
        xs[i][lane] = x[(b * C_INc + i) * HWc + base + lane];
    }
    __syncthreads();

    float acc[32];
    #pragma unroll
    for (int cc = 0; cc < 32; ++cc) acc[cc] = 0.f;

    for (int i4 = 0; i4 < 16; ++i4) {
        float x0 = xs[i4 * 4 + 0][lane];
        float x1 = xs[i4 * 4 + 1][lane];
        float x2 = xs[i4 * 4 + 2][lane];
        float x3 = xs[i4 * 4 + 3][lane];
        #pragma unroll
        for (int cc = 0; cc < 32; ++cc) {
            float4 wv = *reinterpret_cast<const float4*>(
                &w_in[(cg * 32 + cc) * C_INc + i4 * 4]);
            acc[cc] += wv.x * x0 + wv.y * x1 + wv.z * x2 + wv.w * x3;
        }
    }

    float s1 = 0.f, s2 = 0.f;
    #pragma unroll
    for (int cc = 0; cc < 32; ++cc) { s1 += acc[cc]; s2 += acc[cc] * acc[cc]; }
    __shared__ float r1[4][64], r2[4][64];
    r1[cg][lane] = s1; r2[cg][lane] = s2;
    __syncthreads();
    float m   = (r1[0][lane] + r1[1][lane] + r1[2][lane] + r1[3][lane]) * (1.f / C_Hc);
    float ex2 = (r2[0][lane] + r2[1][lane] + r2[2][lane] + r2[3][lane]) * (1.f / C_Hc);
    float rs  = rsqrtf(ex2 - m * m + EPSV);

    long long tbase = ((long long)((b << 14) + base + lane) << 7) + cg * 32;
    #pragma unroll
    for (int cc = 0; cc < 32; cc += 2) {
        int c0 = cg * 32 + cc;
        float y0 = (acc[cc]     - m) * rs * lng[c0]     + lnb[c0];
        float y1 = (acc[cc + 1] - m) * rs * lng[c0 + 1] + lnb[c0 + 1];
        if (!simg) {
            featr[(long long)(b * C_Hc + c0) * HWc + base + lane]     = y0;
            featr[(long long)(b * C_Hc + c0 + 1) * HWc + base + lane] = y1;
        }
        *reinterpret_cast<uint*>(&fT[tbase + cc]) =
            (uint)f2bf(y0) | ((uint)f2bf(y1) << 16);
    }
}

// ---------------------------------------------------------------------------
// conv3x3 + ReLU: per-tap staged GEMM.  Block = 1 image row (128 px), 512
// threads (8 waves), wave tile 32co x 64px.  LDS: feat 3x130 cols (swizzled)
// + wA tap buffer (T14 reg-prefetch).  Output hT bf16 NHWC.
// ---------------------------------------------------------------------------
__global__ __launch_bounds__(512, 2) void k_conv3(
    const ushort* __restrict__ fTr, const ushort* __restrict__ fTe,
    const ushort* __restrict__ wA,
    ushort* __restrict__ hTr, ushort* __restrict__ hTe)
{
    int bid = blockIdx.x;           // 2s * 2b * 128 rows
    int s = bid >> 8, b = (bid >> 7) & 1, h0 = bid & 127;
    const ushort* fT = s ? fTe : fTr;
    ushort* hT = s ? hTe : hTr;
    int tid = threadIdx.x, lane = tid & 63, wv = tid >> 6;
    int lpx = lane & 15, lk = lane >> 4;
    int co0 = (wv & 3) * 32, px0 = (wv >> 2) * 64;

    __shared__ ushort ft[3 * 130 * 128];    // 99,840 B
    __shared__ ushort wk[128 * 128];        // 32,768 B

    const long long ibase = (long long)(b << 14);

    // stage feat tile rows h0-1..h0+1, cols -1..128 (lds col 0..129)
    for (int i = tid; i < 3 * 130 * 16; i += 512) {
        int chunk = i & 15;
        int cr = i >> 4;
        int col = cr % 130, row = cr / 130;
        int gh = h0 + row - 1, gw = col - 1;
        uint4 v = make_uint4(0, 0, 0, 0);
        if ((unsigned)gh < 128u && (unsigned)gw < 128u)
            v = *reinterpret_cast<const uint4*>(
                &fT[((ibase + (gh << 7) + gw) << 7) + (chunk << 3)]);
        int sw = chunk ^ (col & 7);
        *reinterpret_cast<uint4*>(&ft[(((row * 130 + col) << 4) + sw) << 3]) = v;
    }

    // prefetch wA[0] (source-permuted so LDS slot s holds chunk s^(co&7))
    uint4 wpre[4];
    #pragma unroll
    for (int t = 0; t < 4; ++t) {
        int j = tid + (t << 9);
        int co = j >> 4, slot = j & 15;
        wpre[t] = *reinterpret_cast<const uint4*>(
            &wA[(co << 7) + ((slot ^ (co & 7)) << 3)]);
    }
    __syncthreads();
    #pragma unroll
    for (int t = 0; t < 4; ++t)
        *reinterpret_cast<uint4*>(&wk[(tid + (t << 9)) << 3]) = wpre[t];
    __syncthreads();

    f32x4 acc[2][4];
    #pragma unroll
    for (int f = 0; f < 2; ++f)
        #pragma unroll
        for (int p = 0; p < 4; ++p) acc[f][p] = f32x4{0.f, 0.f, 0.f, 0.f};

    for (int tap = 0; tap < 9; ++tap) {
        int ki = tap / 3, kj = tap - ki * 3;
        if (tap < 8) {
            const ushort* srcb = &wA[(tap + 1) << 14];
            #pragma unroll
            for (int t = 0; t < 4; ++t) {
                int j = tid + (t << 9);
                int co = j >> 4, slot = j & 15;
                wpre[t] = *reinterpret_cast<const uint4*>(
                    &srcb[(co << 7) + ((slot ^ (co & 7)) << 3)]);
            }
        }
        short8 a[2][4];
        #pragma unroll
        for (int f = 0; f < 2; ++f) {
            int co = co0 + f * 16 + lpx;
            #pragma unroll
            for (int q = 0; q < 4; ++q)
                a[f][q] = *reinterpret_cast<const short8*>(
                    &wk[((co << 4) + ((q * 4 + lk) ^ (co & 7))) << 3]);
        }
        #pragma unroll
        for (int p = 0; p < 4; ++p) {
            int col = px0 + p * 16 + lpx + kj;     // 0..129
            short8 bq[4];
            #pragma unroll
            for (int q = 0; q < 4; ++q)
                bq[q] = *reinterpret_cast<const short8*>(
                    &ft[(((ki * 130 + col) << 4) + ((q * 4 + lk) ^ (col & 7))) << 3]);
            #pragma unroll
            for (int f = 0; f < 2; ++f)
                #pragma unroll
                for (int q = 0; q < 4; ++q)
                    acc[f][p] = __builtin_amdgcn_mfma_f32_16x16x32_bf16(
                        a[f][q], bq[q], acc[f][p], 0, 0, 0);
        }
        __syncthreads();       // all reads of wk done
        if (tap < 8) {
            #pragma unroll
            for (int t = 0; t < 4; ++t)
                *reinterpret_cast<uint4*>(&wk[(tid + (t << 9)) << 3]) = wpre[t];
        }
        __syncthreads();       // wk[tap+1] ready
    }

    long long obase = (ibase + ((long long)h0 << 7)) << 7;
    #pragma unroll
    for (int f = 0; f < 2; ++f)
        #pragma unroll
        for (int p = 0; p < 4; ++p) {
            int c  = co0 + f * 16 + (lk << 2);
            int px = px0 + p * 16 + lpx;
            float v0 = fmaxf(acc[f][p][0], 0.f), v1 = fmaxf(acc[f][p][1], 0.f);
            float v2 = fmaxf(acc[f][p][2], 0.f), v3 = fmaxf(acc[f][p][3], 0.f);
            ushort* dst = &hT[obase + ((long long)px << 7) + c];
            *reinterpret_cast<uint*>(&dst[0]) = (uint)f2bf(v0) | ((uint)f2bf(v1) << 16);
            *reinterpret_cast<uint*>(&dst[2]) = (uint)f2bf(v2) | ((uint)f2bf(v3) << 16);
        }
}

// ---------------------------------------------------------------------------
// Fused dynamic-filter.  Block = 1 row (128co x 128px), 256 threads (4 waves),
// wave tile 64co x 64px.  h B-frags persistent in registers; w2b[k] staged by
// global_load_lds into double-buffered swizzled LDS; one barrier per tap.
// ---------------------------------------------------------------------------
__global__ __launch_bounds__(BLK, 2) void k_dfapply(
    const ushort* __restrict__ hTr, const ushort* __restrict__ hTe,
    const ushort* __restrict__ fTr, const ushort* __restrict__ fTe,
    const ushort* __restrict__ w2b,
    ushort* __restrict__ enhr, ushort* __restrict__ enhe)
{
    int bid = blockIdx.x;           // 2s * 2b * 128 rows
    int s = bid >> 8, b = (bid >> 7) & 1, h0 = bid & 127;
    const ushort* hT = s ? hTe : hTr;
    const ushort* fT = s ? fTe : fTr;
    ushort* enh = s ? enhe : enhr;
    int tid = threadIdx.x, lane = tid & 63, wv = tid >> 6;
    int lpx = lane & 15, lk = lane >> 4;
    int co0 = (wv & 1) * 64, px0 = (wv >> 1) * 64;

    __shared__ ushort wk[2][128 * 128];     // 2 x 32 KB

    const long long ibase = (long long)(b << 14);
    const long long rowbase = (ibase + ((long long)h0 << 7)) << 7;

    // persistent B fragments (h tile) straight from global (L2)
    short8 bq[4][4];
    #pragma unroll
    for (int p = 0; p < 4; ++p) {
        int px = px0 + p * 16 + lpx;
        #pragma unroll
        for (int q = 0; q < 4; ++q)
            bq[p][q] = *reinterpret_cast<const short8*>(
                &hT[rowbase + ((long long)px << 7) + ((q * 4 + lk) << 3)]);
    }

    // DMA-stage wk[0] for k=0 (source-permuted -> swizzled content)
    #pragma unroll
    for (int t = 0; t < 8; ++t) {
        int j = tid + (t << 8);
        int co = j >> 4, slot = j & 15;
        gload16(&w2b[(co << 7) + ((slot ^ (co & 7)) << 3)], &wk[0][j << 3]);
    }
    __syncthreads();   // drains DMA + bq loads

    f32x4 osum[4][4];
    #pragma unroll
    for (int f = 0; f < 4; ++f)
        #pragma unroll
        for (int p = 0; p < 4; ++p) osum[f][p] = f32x4{0.f, 0.f, 0.f, 0.f};

    for (int k = 0; k < 25; ++k) {
        int cur = k & 1;
        if (k < 24) {   // DMA prefetch k+1 into other buffer
            const ushort* srcb = &w2b[(k + 1) << 14];
            #pragma unroll
            for (int t = 0; t < 8; ++t) {
                int j = tid + (t << 8);
                int co = j >> 4, slot = j & 15;
                gload16(&srcb[(co << 7) + ((slot ^ (co & 7)) << 3)],
                        &wk[cur ^ 1][j << 3]);
            }
        }
        int k5 = k / 5;
        int dh = k5 - 2, dw = k - k5 * 5 - 2;
        int gh = h0 + dh;
        bool rowok = (unsigned)gh < 128u;
        const ushort* fprow = fT + ((ibase + ((long long)gh << 7)) << 7);

        uint2 featv[4][4];
        #pragma unroll
        for (int p = 0; p < 4; ++p) {
            int gw = px0 + p * 16 + lpx + dw;
            bool ok = rowok && ((unsigned)gw < 128u);
            #pragma unroll
            for (int f = 0; f < 4; ++f) {
                uint2 v = make_uint2(0, 0);
                if (ok) v = *reinterpret_cast<const uint2*>(
                    &fprow[((long long)gw << 7) + co0 + f * 16 + (lk << 2)]);
                featv[p][f] = v;
            }
        }

        #pragma unroll
        for (int f = 0; f < 4; ++f) {
            int co = co0 + f * 16 + lpx;
            short8 a[4];
            #pragma unroll
            for (int q = 0; q < 4; ++q)
                a[q] = *reinterpret_cast<const short8*>(
                    &wk[cur][((co << 4) + ((q * 4 + lk) ^ (co & 7))) << 3]);
            #pragma unroll
            for (int p = 0; p < 4; ++p) {
                f32x4 fac = f32x4{0.f, 0.f, 0.f, 0.f};
                #pragma unroll
                for (int q = 0; q < 4; ++q)
                    fac = __builtin_amdgcn_mfma_f32_16x16x32_bf16(
                        a[q], bq[p][q], fac, 0, 0, 0);
                uint2 fv = featv[p][f];
                osum[f][p][0] += fac[0] * bf2f((ushort)(fv.x & 0xffff));
                osum[f][p][1] += fac[1] * bf2f((ushort)(fv.x >> 16));
                osum[f][p][2] += fac[2] * bf2f((ushort)(fv.y & 0xffff));
                osum[f][p][3] += fac[3] * bf2f((ushort)(fv.y >> 16));
            }
        }
        __syncthreads();   // DMA k+1 landed; all reads of wk[cur] done
    }

    #pragma unroll
    for (int f = 0; f < 4; ++f)
        #pragma unroll
        for (int p = 0; p < 4; ++p) {
            int c   = co0 + f * 16 + (lk << 2);
            int pxl = px0 + p * 16 + lpx;
            #pragma unroll
            for (int r = 0; r < 4; ++r)
                enh[(((long long)(b << 7) + c + r) << 14) + (h0 << 7) + pxl] =
                    f2bf(osum[f][p][r]);
        }
}

// ---------------------------------------------------------------------------
// Tail: sp conv + sigmoid gate + fuse + LN + out conv.  fp32.
// ---------------------------------------------------------------------------
__global__ __launch_bounds__(BLK) void k_final(
    const ushort* __restrict__ enh_r, const ushort* __restrict__ enh_e,
    const float* __restrict__ featr, const float* __restrict__ w_sp,
    const float* __restrict__ lng, const float* __restrict__ lnb,
    const float* __restrict__ w_out, float* __restrict__ out)
{
    int bid  = blockIdx.x;  // Bb * 256
    int b    = bid >> 8;
    int base = (bid & 255) * 64;
    int lane = threadIdx.x & 63;
    int cg   = threadIdx.x >> 6;

    __shared__ float es[C_Hc][64];
    #pragma unroll
    for (int r = 0; r < 32; ++r) {
        int j = cg * 32 + r;
        es[j][lane] = bf2f(enh_e[(long long)(b * C_Hc + j) * HWc + base + lane]);
    }
    __syncthreads();

    float sacc[32];
    #pragma unroll
    for (int cc = 0; cc < 32; ++cc) sacc[cc] = 0.f;
    for (int j4 = 0; j4 < 32; ++j4) {
        float x0 = es[j4 * 4 + 0][lane];
        float x1 = es[j4 * 4 + 1][lane];
        float x2 = es[j4 * 4 + 2][lane];
        float x3 = es[j4 * 4 + 3][lane];
        #pragma unroll
        for (int cc = 0; cc < 32; ++cc) {
            float4 wv = *reinterpret_cast<const float4*>(
                &w_sp[(cg * 32 + cc) * C_Hc + j4 * 4]);
            sacc[cc] += wv.x * x0 + wv.y * x1 + wv.z * x2 + wv.w * x3;
        }
    }

    float fu[32];
    float s1 = 0.f, s2 = 0.f;
    #pragma unroll
    for (int cc = 0; cc < 32; ++cc) {
        int c = cg * 32 + cc;
        long long off = (long long)(b * C_Hc + c) * HWc + base + lane;
        float re = bf2f(enh_r[off]);
        float rf = featr[off];
        float sg = 1.f / (1.f + __expf(-sacc[cc]));
        float f  = re + re * sg + rf;
        fu[cc] = f;
        s1 += f; s2 += f * f;
    }
    __shared__ float r1[4][64], r2[4][64];
    r1[cg][lane] = s1; r2[cg][lane] = s2;
    __syncthreads();
    float m   = (r1[0][lane] + r1[1][lane] + r1[2][lane] + r1[3][lane]) * (1.f / C_Hc);
    float ex2 = (r2[0][lane] + r2[1][lane] + r2[2][lane] + r2[3][lane]) * (1.f / C_Hc);
    float rs  = rsqrtf(ex2 - m * m + EPSV);

    #pragma unroll
    for (int cc = 0; cc < 32; ++cc) {
        int c = cg * 32 + cc;
        es[c][lane] = (fu[cc] - m) * rs * lng[c] + lnb[c];
    }
    __syncthreads();

    float oacc[16];
    #pragma unroll
    for (int oo = 0; oo < 16; ++oo) oacc[oo] = 0.f;
    for (int j4 = 0; j4 < 32; ++j4) {
        float x0 = es[j4 * 4 + 0][lane];
        float x1 = es[j4 * 4 + 1][lane];
        float x2 = es[j4 * 4 + 2][lane];
        float x3 = es[j4 * 4 + 3][lane];
        #pragma unroll
        for (int oo = 0; oo < 16; ++oo) {
            int o = cg * 16 + oo;
            float4 wv = *reinterpret_cast<const float4*>(
                &w_out[o * C_Hc + j4 * 4]);
            oacc[oo] += wv.x * x0 + wv.y * x1 + wv.z * x2 + wv.w * x3;
        }
    }
    #pragma unroll
    for (int oo = 0; oo < 16; ++oo)
        out[(long long)(b * C_INc + cg * 16 + oo) * HWc + base + lane] = oacc[oo];
}

// ---------------------------------------------------------------------------
extern "C" void kernel_launch(void* const* d_in, const int* in_sizes, int n_in,
                              void* d_out, int out_size, void* d_ws, size_t ws_size,
                              hipStream_t stream)
{
    const float* rgb  = (const float*)d_in[0];
    const float* evt  = (const float*)d_in[1];
    const float* w_in = (const float*)d_in[2];
    const float* lng  = (const float*)d_in[3];
    const float* lnb  = (const float*)d_in[4];
    const float* w1   = (const float*)d_in[5];
    const float* w2   = (const float*)d_in[6];
    const float* wsp  = (const float*)d_in[7];
    const float* wout = (const float*)d_in[8];
    float* out = (float*)d_out;

    float* ws = (float*)d_ws;
    float*  featr = ws;                              // 4,194,304 f
    ushort* fTr   = (ushort*)(ws + 4194304);
    ushort* fTe   = (ushort*)(ws + 6291456);
    ushort* hTr   = (ushort*)(ws + 8388608);
    ushort* hTe   = (ushort*)(ws + 10485760);
    ushort* enhr  = (ushort*)(ws + 12582912);
    ushort* enhe  = (ushort*)(ws + 14680064);
    ushort* wA    = (ushort*)(ws + 16777216);        // 147,456 bf16
    ushort* w2b   = (ushort*)(ws + 16850944);        // 409,600 bf16

    k_prep<<<2176, BLK, 0, stream>>>(w1, w2, wA, w2b);
    k_in_ln<<<2 * Bb * 256, BLK, 0, stream>>>(rgb, evt, w_in, lng, lnb,
                                              featr, fTr, fTe);
    k_conv3<<<512, 512, 0, stream>>>(fTr, fTe, wA, hTr, hTe);
    k_dfapply<<<512, BLK, 0, stream>>>(hTr, hTe, fTr, fTe, w2b, enhr, enhe);
    k_final<<<Bb * 256, BLK, 0, stream>>>(enhr, enhe, featr, wsp, lng, lnb,
                                          wout, out);
}

// Round 5
// 321.304 us; speedup vs baseline: 14.4696x; 1.1557x over previous
//
#include <hip/hip_runtime.h>
#include <math.h>

#define BLK 256

typedef unsigned short ushort;
typedef unsigned int uint;
typedef __attribute__((ext_vector_type(8))) short short8;
typedef __attribute__((ext_vector_type(4))) float f32x4;

constexpr int C_Hc = 128;
constexpr int C_INc = 64;
constexpr int Hh = 128;
constexpr int Ww = 128;
constexpr int HWc = Hh * Ww;   // 16384
constexpr int Bb = 2;
constexpr float EPSV = 1e-5f;

__device__ __forceinline__ float bf2f(ushort u) {
    union { uint u32; float f; } v; v.u32 = (uint)u << 16; return v.f;
}
__device__ __forceinline__ ushort f2bf(float x) {
    union { float f; uint u; } v; v.f = x;
    uint r = (v.u + 0x7FFFu + ((v.u >> 16) & 1u)) >> 16;
    return (ushort)r;
}
__device__ __forceinline__ uint pack2(float a, float b) {
    return (uint)f2bf(a) | ((uint)f2bf(b) << 16);
}
__device__ __forceinline__ void gload16(const ushort* g, ushort* l) {
    __builtin_amdgcn_global_load_lds(
        (const __attribute__((address_space(1))) void*)g,
        (__attribute__((address_space(3))) void*)l, 16, 0, 0);
}

// ---------------------------------------------------------------------------
// Weight prep (chunk-major bf16: [chunk][co][8], chunk = ci/8):
//   wA[tap][16][128][8], w2b[k][16][128][8], wspb[16][128][8]
// ---------------------------------------------------------------------------
__global__ __launch_bounds__(BLK) void k_prep(
    const float* __restrict__ w1, const float* __restrict__ w2,
    const float* __restrict__ wsp,
    ushort* __restrict__ wA, ushort* __restrict__ w2b,
    ushort* __restrict__ wspb)
{
    int idx = blockIdx.x * BLK + threadIdx.x;
    if (idx < 147456) {                       // wA: 9 * 16384
        int tap = idx >> 14, r = idx & 16383;
        int chunk = r >> 10, co = (r >> 3) & 127, e = r & 7;
        int ci = chunk * 8 + e;
        wA[idx] = f2bf(w1[(co * 128 + ci) * 9 + tap]);
    } else if (idx < 557056) {                // w2b: 25 * 16384
        int o = idx - 147456;
        int k = o >> 14, r = o & 16383;
        int chunk = r >> 10, co = (r >> 3) & 127, e = r & 7;
        int ci = chunk * 8 + e;
        w2b[o] = f2bf(w2[(co * 25 + k) * 128 + ci]);
    } else if (idx < 573440) {                // wspb: 16384
        int o = idx - 557056;
        int chunk = o >> 10, co = (o >> 3) & 127, e = o & 7;
        wspb[o] = f2bf(wsp[co * 128 + chunk * 8 + e]);
    }
}

// ---------------------------------------------------------------------------
// conv1x1(w_in) + LayerNorm; writes featT bf16 NHWC (both streams) and
// featrT fp32 NHWC (rgb only, fp32 residual for the tail).
// ---------------------------------------------------------------------------
__global__ __launch_bounds__(BLK) void k_in_ln(
    const float* __restrict__ xr, const float* __restrict__ xe,
    const float* __restrict__ w_in, const float* __restrict__ lng,
    const float* __restrict__ lnb,
    ushort* __restrict__ fTr, ushort* __restrict__ fTe,
    float* __restrict__ featrT)
{
    int bid  = blockIdx.x;          // 2 * Bb * 256
    int simg = bid >> 9;
    int rem  = bid & 511;
    int b    = rem >> 8;
    int base = (rem & 255) * 64;
    const float* x = simg ? xe : xr;
    ushort* fT = simg ? fTe : fTr;
    int lane = threadIdx.x & 63;
    int cg   = threadIdx.x >> 6;

    __shared__ float xs[C_INc][64];
    #pragma unroll
    for (int r = 0; r < 16; ++r) {
        int i = cg * 16 + r;
        xs[i][lane] = x[(b * C_INc + i) * HWc + base + lane];
    }
    __syncthreads();

    float acc[32];
    #pragma unroll
    for (int cc = 0; cc < 32; ++cc) acc[cc] = 0.f;

    for (int i4 = 0; i4 < 16; ++i4) {
        float x0 = xs[i4 * 4 + 0][lane];
        float x1 = xs[i4 * 4 + 1][lane];
        float x2 = xs[i4 * 4 + 2][lane];
        float x3 = xs[i4 * 4 + 3][lane];
        #pragma unroll
        for (int cc = 0; cc < 32; ++cc) {
            float4 wv = *reinterpret_cast<const float4*>(
                &w_in[(cg * 32 + cc) * C_INc + i4 * 4]);
            acc[cc] += wv.x * x0 + wv.y * x1 + wv.z * x2 + wv.w * x3;
        }
    }

    float s1 = 0.f, s2 = 0.f;
    #pragma unroll
    for (int cc = 0; cc < 32; ++cc) { s1 += acc[cc]; s2 += acc[cc] * acc[cc]; }
    __shared__ float r1[4][64], r2[4][64];
    r1[cg][lane] = s1; r2[cg][lane] = s2;
    __syncthreads();
    float m   = (r1[0][lane] + r1[1][lane] + r1[2][lane] + r1[3][lane]) * (1.f / C_Hc);
    float ex2 = (r2[0][lane] + r2[1][lane] + r2[2][lane] + r2[3][lane]) * (1.f / C_Hc);
    float rs  = rsqrtf(ex2 - m * m + EPSV);

    long long tbase = ((long long)((b << 14) + base + lane) << 7) + cg * 32;
    #pragma unroll
    for (int cc = 0; cc < 32; cc += 4) {
        int c0 = cg * 32 + cc;
        float4 g4 = *reinterpret_cast<const float4*>(&lng[c0]);
        float4 b4 = *reinterpret_cast<const float4*>(&lnb[c0]);
        float4 y;
        y.x = (acc[cc + 0] - m) * rs * g4.x + b4.x;
        y.y = (acc[cc + 1] - m) * rs * g4.y + b4.y;
        y.z = (acc[cc + 2] - m) * rs * g4.z + b4.z;
        y.w = (acc[cc + 3] - m) * rs * g4.w + b4.w;
        *reinterpret_cast<uint*>(&fT[tbase + cc])     = pack2(y.x, y.y);
        *reinterpret_cast<uint*>(&fT[tbase + cc + 2]) = pack2(y.z, y.w);
        if (!simg)
            *reinterpret_cast<float4*>(&featrT[tbase + cc]) = y;
    }
}

// ---------------------------------------------------------------------------
// conv3x3 + ReLU: per-tap staged GEMM.  Block = 1 image row, 512 threads
// (8 waves), wave tile 32co x 64px.  LDS chunk-major (conflict-free b128).
// ---------------------------------------------------------------------------
__global__ __launch_bounds__(512, 2) void k_conv3(
    const ushort* __restrict__ fTr, const ushort* __restrict__ fTe,
    const ushort* __restrict__ wA,
    ushort* __restrict__ hTr, ushort* __restrict__ hTe)
{
    int bid = blockIdx.x;           // 2s * 2b * 128 rows
    int s = bid >> 8, b = (bid >> 7) & 1, h0 = bid & 127;
    const ushort* fT = s ? fTe : fTr;
    ushort* hT = s ? hTe : hTr;
    int tid = threadIdx.x, lane = tid & 63, wv = tid >> 6;
    int lpx = lane & 15, lk = lane >> 4;
    int co0 = (wv & 3) * 32, px0 = (wv >> 2) * 64;

    __shared__ ushort ft[16 * 390 * 8];     // chunk-major: [chunk][row*130+col][8]
    __shared__ ushort wk[16 * 128 * 8];     // chunk-major: [chunk][co][8]

    const long long ibase = (long long)(b << 14);

    // stage feat tile rows h0-1..h0+1, cols -1..128 (lds col 0..129)
    for (int i = tid; i < 6240; i += 512) {
        int chunk = i / 390;
        int rem = i - chunk * 390;
        int row = rem / 130, col = rem - row * 130;
        int gh = h0 + row - 1, gw = col - 1;
        uint4 v = make_uint4(0, 0, 0, 0);
        if ((unsigned)gh < 128u && (unsigned)gw < 128u)
            v = *reinterpret_cast<const uint4*>(
                &fT[((ibase + (gh << 7) + gw) << 7) + (chunk << 3)]);
        *reinterpret_cast<uint4*>(&ft[i << 3]) = v;
    }

    // prefetch wA[0] (already chunk-major in global)
    uint4 wpre[4];
    #pragma unroll
    for (int t = 0; t < 4; ++t)
        wpre[t] = *reinterpret_cast<const uint4*>(&wA[(tid + (t << 9)) << 3]);
    __syncthreads();
    #pragma unroll
    for (int t = 0; t < 4; ++t)
        *reinterpret_cast<uint4*>(&wk[(tid + (t << 9)) << 3]) = wpre[t];
    __syncthreads();

    f32x4 acc[2][4];
    #pragma unroll
    for (int f = 0; f < 2; ++f)
        #pragma unroll
        for (int p = 0; p < 4; ++p) acc[f][p] = f32x4{0.f, 0.f, 0.f, 0.f};

    for (int tap = 0; tap < 9; ++tap) {
        int ki = tap / 3, kj = tap - ki * 3;
        if (tap < 8) {
            const ushort* srcb = &wA[(tap + 1) << 14];
            #pragma unroll
            for (int t = 0; t < 4; ++t)
                wpre[t] = *reinterpret_cast<const uint4*>(
                    &srcb[(tid + (t << 9)) << 3]);
        }
        short8 a[2][4];
        #pragma unroll
        for (int f = 0; f < 2; ++f) {
            int co = co0 + f * 16 + lpx;
            #pragma unroll
            for (int q = 0; q < 4; ++q)
                a[f][q] = *reinterpret_cast<const short8*>(
                    &wk[(((q * 4 + lk) << 7) + co) << 3]);
        }
        #pragma unroll
        for (int p = 0; p < 4; ++p) {
            int col = px0 + p * 16 + lpx + kj;     // 0..129
            short8 bq[4];
            #pragma unroll
            for (int q = 0; q < 4; ++q)
                bq[q] = *reinterpret_cast<const short8*>(
                    &ft[((q * 4 + lk) * 390 + ki * 130 + col) << 3]);
            #pragma unroll
            for (int f = 0; f < 2; ++f)
                #pragma unroll
                for (int q = 0; q < 4; ++q)
                    acc[f][p] = __builtin_amdgcn_mfma_f32_16x16x32_bf16(
                        a[f][q], bq[q], acc[f][p], 0, 0, 0);
        }
        __syncthreads();       // all reads of wk done
        if (tap < 8) {
            #pragma unroll
            for (int t = 0; t < 4; ++t)
                *reinterpret_cast<uint4*>(&wk[(tid + (t << 9)) << 3]) = wpre[t];
        }
        __syncthreads();       // wk[tap+1] ready
    }

    long long obase = (ibase + ((long long)h0 << 7)) << 7;
    #pragma unroll
    for (int f = 0; f < 2; ++f)
        #pragma unroll
        for (int p = 0; p < 4; ++p) {
            int c  = co0 + f * 16 + (lk << 2);
            int px = px0 + p * 16 + lpx;
            float v0 = fmaxf(acc[f][p][0], 0.f), v1 = fmaxf(acc[f][p][1], 0.f);
            float v2 = fmaxf(acc[f][p][2], 0.f), v3 = fmaxf(acc[f][p][3], 0.f);
            ushort* dst = &hT[obase + ((long long)px << 7) + c];
            *reinterpret_cast<uint*>(&dst[0]) = pack2(v0, v1);
            *reinterpret_cast<uint*>(&dst[2]) = pack2(v2, v3);
        }
}

// ---------------------------------------------------------------------------
// Fused dynamic-filter.  Block = 1 row (128co x 128px), 256 threads (4 waves),
// wave tile 64co x 64px (proven R3 shape: ~116 VGPR, 2 blocks/CU).
// Chunk-major LDS (conflict-free); w2b[k] DMA double-buffered; 1 barrier/tap.
// Output enh bf16 NHWC.
// ---------------------------------------------------------------------------
__global__ __launch_bounds__(BLK, 2) void k_dfapply(
    const ushort* __restrict__ hTr, const ushort* __restrict__ hTe,
    const ushort* __restrict__ fTr, const ushort* __restrict__ fTe,
    const ushort* __restrict__ w2b,
    ushort* __restrict__ enhr, ushort* __restrict__ enhe)
{
    int bid = blockIdx.x;           // 2s * 2b * 128 rows
    int s = bid >> 8, b = (bid >> 7) & 1, h0 = bid & 127;
    const ushort* hT = s ? hTe : hTr;
    const ushort* fT = s ? fTe : fTr;
    ushort* enh = s ? enhe : enhr;
    int tid = threadIdx.x, lane = tid & 63, wv = tid >> 6;
    int lpx = lane & 15, lk = lane >> 4;
    int co0 = (wv & 1) * 64, px0 = (wv >> 1) * 64;

    __shared__ ushort wk[2][16 * 128 * 8];       // 2 x 32 KB chunk-major

    const long long ibase = (long long)(b << 14);
    const long long rowbase = (ibase + ((long long)h0 << 7)) << 7;

    // persistent B fragments (h tile) from global (L2)
    short8 bq[4][4];
    #pragma unroll
    for (int p = 0; p < 4; ++p) {
        int px = px0 + p * 16 + lpx;
        #pragma unroll
        for (int q = 0; q < 4; ++q)
            bq[p][q] = *reinterpret_cast<const short8*>(
                &hT[rowbase + ((long long)px << 7) + ((q * 4 + lk) << 3)]);
    }

    // DMA-stage wk[0] for k=0 (chunk-major -> fully contiguous)
    #pragma unroll
    for (int t = 0; t < 8; ++t) {
        int j = tid + (t << 8);
        gload16(&w2b[j << 3], &wk[0][j << 3]);
    }
    __syncthreads();

    f32x4 osum[4][4];
    #pragma unroll
    for (int f = 0; f < 4; ++f)
        #pragma unroll
        for (int p = 0; p < 4; ++p) osum[f][p] = f32x4{0.f, 0.f, 0.f, 0.f};

    for (int k = 0; k < 25; ++k) {
        int cur = k & 1;
        if (k < 24) {   // DMA prefetch k+1 into other buffer
            const ushort* srcb = &w2b[(k + 1) << 14];
            #pragma unroll
            for (int t = 0; t < 8; ++t) {
                int j = tid + (t << 8);
                gload16(&srcb[j << 3], &wk[cur ^ 1][j << 3]);
            }
        }
        int k5 = k / 5;
        int dh = k5 - 2, dw = k - k5 * 5 - 2;
        int gh = h0 + dh;
        bool rowok = (unsigned)gh < 128u;
        const ushort* fprow = fT + ((ibase + ((long long)gh << 7)) << 7);

        uint2 featv[4][4];
        #pragma unroll
        for (int p = 0; p < 4; ++p) {
            int gw = px0 + p * 16 + lpx + dw;
            bool ok = rowok && ((unsigned)gw < 128u);
            #pragma unroll
            for (int f = 0; f < 4; ++f) {
                uint2 v = make_uint2(0, 0);
                if (ok) v = *reinterpret_cast<const uint2*>(
                    &fprow[((long long)gw << 7) + co0 + f * 16 + (lk << 2)]);
                featv[p][f] = v;
            }
        }

        #pragma unroll
        for (int f = 0; f < 4; ++f) {
            int co = co0 + f * 16 + lpx;
            short8 a[4];
            #pragma unroll
            for (int q = 0; q < 4; ++q)
                a[q] = *reinterpret_cast<const short8*>(
                    &wk[cur][(((q * 4 + lk) << 7) + co) << 3]);
            __builtin_amdgcn_s_setprio(1);
            #pragma unroll
            for (int p = 0; p < 4; ++p) {
                f32x4 fac = f32x4{0.f, 0.f, 0.f, 0.f};
                #pragma unroll
                for (int q = 0; q < 4; ++q)
                    fac = __builtin_amdgcn_mfma_f32_16x16x32_bf16(
                        a[q], bq[p][q], fac, 0, 0, 0);
                uint2 fv = featv[p][f];
                osum[f][p][0] += fac[0] * bf2f((ushort)(fv.x & 0xffff));
                osum[f][p][1] += fac[1] * bf2f((ushort)(fv.x >> 16));
                osum[f][p][2] += fac[2] * bf2f((ushort)(fv.y & 0xffff));
                osum[f][p][3] += fac[3] * bf2f((ushort)(fv.y >> 16));
            }
            __builtin_amdgcn_s_setprio(0);
        }
        __syncthreads();   // DMA k+1 landed; all reads of wk[cur] done
    }

    // store enh NHWC bf16
    #pragma unroll
    for (int f = 0; f < 4; ++f)
        #pragma unroll
        for (int p = 0; p < 4; ++p) {
            int c  = co0 + f * 16 + (lk << 2);
            int px = px0 + p * 16 + lpx;
            uint2 o;
            o.x = pack2(osum[f][p][0], osum[f][p][1]);
            o.y = pack2(osum[f][p][2], osum[f][p][3]);
            *reinterpret_cast<uint2*>(&enh[rowbase + ((long long)px << 7) + c]) = o;
        }
}

// ---------------------------------------------------------------------------
// Tail: sp = w_sp @ enh_e (bf16 MFMA) -> sigmoid gate -> + fp32 feat residual
// -> LN (fp32) -> out conv (fp32 VALU, SGPR-broadcast weights).
// Block = 64 px, 256 threads (4 waves).  No LDS buffer reused after read.
// ---------------------------------------------------------------------------
__global__ __launch_bounds__(BLK, 2) void k_final(
    const ushort* __restrict__ enhr, const ushort* __restrict__ enhe,
    const float* __restrict__ featrT,
    const ushort* __restrict__ wspb, const float* __restrict__ w_out,
    const float* __restrict__ lng, const float* __restrict__ lnb,
    float* __restrict__ out)
{
    int bid = blockIdx.x;            // Bb * 256
    int b = bid >> 8;
    int px0g = (bid & 255) * 64;     // linear pixel base
    int tid = threadIdx.x, lane = tid & 63, wv = tid >> 6;
    int lpx = lane & 15, lk = lane >> 4;

    __shared__ ushort es[16 * 64 * 8];    // enh_e chunk-major (16 KB)
    __shared__ float xs[128][64];         // fp32 normalized fused (32 KB)
    __shared__ float p1[4][64], p2[4][64];

    const long long ebase = ((long long)((b << 14) + px0g)) << 7;

    #pragma unroll
    for (int t = 0; t < 4; ++t) {
        int j = tid + (t << 8);
        int chunk = j >> 6, px = j & 63;
        *reinterpret_cast<uint4*>(&es[j << 3]) =
            *reinterpret_cast<const uint4*>(
                &enhe[ebase + ((long long)px << 7) + (chunk << 3)]);
    }
    __syncthreads();

    // sp GEMM: wave-tile 32co x 64px (co0 = wv*32); A-frags direct from global
    int co0 = wv * 32;
    f32x4 sp[2][4];
    #pragma unroll
    for (int f = 0; f < 2; ++f)
        #pragma unroll
        for (int p = 0; p < 4; ++p) sp[f][p] = f32x4{0.f, 0.f, 0.f, 0.f};
    #pragma unroll
    for (int q = 0; q < 4; ++q) {
        short8 a[2], bb[4];
        #pragma unroll
        for (int f = 0; f < 2; ++f)
            a[f] = *reinterpret_cast<const short8*>(
                &wspb[((((q * 4 + lk) << 7) + co0 + f * 16 + lpx)) << 3]);
        #pragma unroll
        for (int p = 0; p < 4; ++p)
            bb[p] = *reinterpret_cast<const short8*>(
                &es[((((q * 4 + lk) << 6) + p * 16 + lpx)) << 3]);
        #pragma unroll
        for (int f = 0; f < 2; ++f)
            #pragma unroll
            for (int p = 0; p < 4; ++p)
                sp[f][p] = __builtin_amdgcn_mfma_f32_16x16x32_bf16(
                    a[f], bb[p], sp[f][p], 0, 0, 0);
    }

    // gate + fuse (fp32 residual) + LN partials
    float fu[2][4][4];
    float s1[4] = {0.f, 0.f, 0.f, 0.f}, s2[4] = {0.f, 0.f, 0.f, 0.f};
    #pragma unroll
    for (int f = 0; f < 2; ++f) {
        int c4 = co0 + f * 16 + (lk << 2);
        #pragma unroll
        for (int p = 0; p < 4; ++p) {
            int px = p * 16 + lpx;
            long long poff = ebase + ((long long)px << 7) + c4;
            uint2 re2 = *reinterpret_cast<const uint2*>(&enhr[poff]);
            float4 rf4 = *reinterpret_cast<const float4*>(&featrT[poff]);
            float re[4] = { bf2f((ushort)(re2.x & 0xffff)), bf2f((ushort)(re2.x >> 16)),
                            bf2f((ushort)(re2.y & 0xffff)), bf2f((ushort)(re2.y >> 16)) };
            float rf[4] = { rf4.x, rf4.y, rf4.z, rf4.w };
            #pragma unroll
            for (int r = 0; r < 4; ++r) {
                float sg = 1.f / (1.f + __expf(-sp[f][p][r]));
                float v = re[r] * (1.f + sg) + rf[r];
                fu[f][p][r] = v;
                s1[p] += v; s2[p] += v * v;
            }
        }
    }
    #pragma unroll
    for (int p = 0; p < 4; ++p) {
        s1[p] += __shfl_xor(s1[p], 16); s1[p] += __shfl_xor(s1[p], 32);
        s2[p] += __shfl_xor(s2[p], 16); s2[p] += __shfl_xor(s2[p], 32);
    }
    if (lk == 0) {
        #pragma unroll
        for (int p = 0; p < 4; ++p) {
            p1[wv][p * 16 + lpx] = s1[p];
            p2[wv][p * 16 + lpx] = s2[p];
        }
    }
    __syncthreads();

    float mm[4], rs[4];
    #pragma unroll
    for (int p = 0; p < 4; ++p) {
        int px = p * 16 + lpx;
        float m   = (p1[0][px] + p1[1][px] + p1[2][px] + p1[3][px]) * (1.f / 128.f);
        float ex2 = (p2[0][px] + p2[1][px] + p2[2][px] + p2[3][px]) * (1.f / 128.f);
        mm[p] = m;
        rs[p] = rsqrtf(ex2 - m * m + EPSV);
    }

    // normalized fused -> xs fp32 [channel][px]
    #pragma unroll
    for (int f = 0; f < 2; ++f) {
        int c4 = co0 + f * 16 + (lk << 2);
        float4 g = *reinterpret_cast<const float4*>(&lng[c4]);
        float4 bta = *reinterpret_cast<const float4*>(&lnb[c4]);
        #pragma unroll
        for (int p = 0; p < 4; ++p) {
            int px = p * 16 + lpx;
            xs[c4 + 0][px] = (fu[f][p][0] - mm[p]) * rs[p] * g.x + bta.x;
            xs[c4 + 1][px] = (fu[f][p][1] - mm[p]) * rs[p] * g.y + bta.y;
            xs[c4 + 2][px] = (fu[f][p][2] - mm[p]) * rs[p] * g.z + bta.z;
            xs[c4 + 3][px] = (fu[f][p][3] - mm[p]) * rs[p] * g.w + bta.w;
        }
    }
    __syncthreads();

    // out conv fp32: wave wv -> co block wv*16; lane = px
    int co0o = wv * 16;
    float oacc[16];
    #pragma unroll
    for (int oo = 0; oo < 16; ++oo) oacc[oo] = 0.f;
    for (int j4 = 0; j4 < 32; ++j4) {
        float x0 = xs[j4 * 4 + 0][lane];
        float x1 = xs[j4 * 4 + 1][lane];
        float x2 = xs[j4 * 4 + 2][lane];
        float x3 = xs[j4 * 4 + 3][lane];
        #pragma unroll
        for (int oo = 0; oo < 16; ++oo) {
            float4 wv4 = *reinterpret_cast<const float4*>(
                &w_out[(co0o + oo) * C_Hc + j4 * 4]);
            oacc[oo] += wv4.x * x0 + wv4.y * x1 + wv4.z * x2 + wv4.w * x3;
        }
    }
    #pragma unroll
    for (int oo = 0; oo < 16; ++oo)
        out[((long long)(b * C_INc + co0o + oo) << 14) + px0g + lane] = oacc[oo];
}

// ---------------------------------------------------------------------------
extern "C" void kernel_launch(void* const* d_in, const int* in_sizes, int n_in,
                              void* d_out, int out_size, void* d_ws, size_t ws_size,
                              hipStream_t stream)
{
    const float* rgb  = (const float*)d_in[0];
    const float* evt  = (const float*)d_in[1];
    const float* w_in = (const float*)d_in[2];
    const float* lng  = (const float*)d_in[3];
    const float* lnb  = (const float*)d_in[4];
    const float* w1   = (const float*)d_in[5];
    const float* w2   = (const float*)d_in[6];
    const float* wsp  = (const float*)d_in[7];
    const float* wout = (const float*)d_in[8];
    float* out = (float*)d_out;

    float* ws = (float*)d_ws;
    ushort* fTr    = (ushort*)(ws);
    ushort* fTe    = (ushort*)(ws + 2097152);
    ushort* hTr    = (ushort*)(ws + 4194304);
    ushort* hTe    = (ushort*)(ws + 6291456);
    ushort* enhr   = (ushort*)(ws + 8388608);
    ushort* enhe   = (ushort*)(ws + 10485760);
    float*  featrT = (float*)(ws + 12582912);   // 4,194,304 f (fp32 NHWC, rgb)
    ushort* wA     = (ushort*)(ws + 16777216);  // 147456 bf16
    ushort* w2b    = (ushort*)(ws + 16850944);  // 409600 bf16
    ushort* wspb   = (ushort*)(ws + 17055744);  // 16384 bf16

    k_prep<<<2240, BLK, 0, stream>>>(w1, w2, wsp, wA, w2b, wspb);
    k_in_ln<<<2 * Bb * 256, BLK, 0, stream>>>(rgb, evt, w_in, lng, lnb,
                                              fTr, fTe, featrT);
    k_conv3<<<512, 512, 0, stream>>>(fTr, fTe, wA, hTr, hTe);
    k_dfapply<<<512, BLK, 0, stream>>>(hTr, hTe, fTr, fTe, w2b, enhr, enhe);
    k_final<<<Bb * 256, BLK, 0, stream>>>(enhr, enhe, featrT, wspb, wout,
                                          lng, lnb, out);
}

// Round 6
// 297.651 us; speedup vs baseline: 15.6194x; 1.0795x over previous
//
#include <hip/hip_runtime.h>
#include <math.h>

#define BLK 256

typedef unsigned short ushort;
typedef unsigned int uint;
typedef __attribute__((ext_vector_type(8))) short short8;
typedef __attribute__((ext_vector_type(4))) float f32x4;

constexpr int C_Hc = 128;
constexpr int C_INc = 64;
constexpr int Hh = 128;
constexpr int Ww = 128;
constexpr int HWc = Hh * Ww;   // 16384
constexpr int Bb = 2;
constexpr float EPSV = 1e-5f;

__device__ __forceinline__ float bf2f(ushort u) {
    union { uint u32; float f; } v; v.u32 = (uint)u << 16; return v.f;
}
__device__ __forceinline__ ushort f2bf(float x) {
    union { float f; uint u; } v; v.f = x;
    uint r = (v.u + 0x7FFFu + ((v.u >> 16) & 1u)) >> 16;
    return (ushort)r;
}
__device__ __forceinline__ uint pack2(float a, float b) {
    return (uint)f2bf(a) | ((uint)f2bf(b) << 16);
}

// ---------------------------------------------------------------------------
// Weight prep (chunk-major bf16: [chunk][co][8], chunk = ci/8):
//   wA[tap][16][128][8], w2b[k][16][128][8], wspb[16][128][8], woutb[16][64][8]
// ---------------------------------------------------------------------------
__global__ __launch_bounds__(BLK) void k_prep(
    const float* __restrict__ w1, const float* __restrict__ w2,
    const float* __restrict__ wsp, const float* __restrict__ wout,
    ushort* __restrict__ wA, ushort* __restrict__ w2b,
    ushort* __restrict__ wspb, ushort* __restrict__ woutb)
{
    int idx = blockIdx.x * BLK + threadIdx.x;
    if (idx < 147456) {                       // wA: 9 * 16384
        int tap = idx >> 14, r = idx & 16383;
        int chunk = r >> 10, co = (r >> 3) & 127, e = r & 7;
        int ci = chunk * 8 + e;
        wA[idx] = f2bf(w1[(co * 128 + ci) * 9 + tap]);
    } else if (idx < 557056) {                // w2b: 25 * 16384
        int o = idx - 147456;
        int k = o >> 14, r = o & 16383;
        int chunk = r >> 10, co = (r >> 3) & 127, e = r & 7;
        int ci = chunk * 8 + e;
        w2b[o] = f2bf(w2[(co * 25 + k) * 128 + ci]);
    } else if (idx < 573440) {                // wspb: 16384
        int o = idx - 557056;
        int chunk = o >> 10, co = (o >> 3) & 127, e = o & 7;
        wspb[o] = f2bf(wsp[co * 128 + chunk * 8 + e]);
    } else if (idx < 581632) {                // woutb: 8192
        int o = idx - 573440;
        int chunk = o >> 9, co = (o >> 3) & 63, e = o & 7;
        woutb[o] = f2bf(wout[co * 128 + chunk * 8 + e]);
    }
}

// ---------------------------------------------------------------------------
// conv1x1(w_in) + LayerNorm; writes featT bf16 NHWC (both streams) and
// featrT fp32 NHWC (rgb only, fp32 residual for the tail).
// ---------------------------------------------------------------------------
__global__ __launch_bounds__(BLK) void k_in_ln(
    const float* __restrict__ xr, const float* __restrict__ xe,
    const float* __restrict__ w_in, const float* __restrict__ lng,
    const float* __restrict__ lnb,
    ushort* __restrict__ fTr, ushort* __restrict__ fTe,
    float* __restrict__ featrT)
{
    int bid  = blockIdx.x;          // 2 * Bb * 256
    int simg = bid >> 9;
    int rem  = bid & 511;
    int b    = rem >> 8;
    int base = (rem & 255) * 64;
    const float* x = simg ? xe : xr;
    ushort* fT = simg ? fTe : fTr;
    int lane = threadIdx.x & 63;
    int cg   = threadIdx.x >> 6;

    __shared__ float xs[C_INc][64];
    #pragma unroll
    for (int r = 0; r < 16; ++r) {
        int i = cg * 16 + r;
        xs[i][lane] = x[(b * C_INc + i) * HWc + base + lane];
    }
    __syncthreads();

    float acc[32];
    #pragma unroll
    for (int cc = 0; cc < 32; ++cc) acc[cc] = 0.f;

    for (int i4 = 0; i4 < 16; ++i4) {
        float x0 = xs[i4 * 4 + 0][lane];
        float x1 = xs[i4 * 4 + 1][lane];
        float x2 = xs[i4 * 4 + 2][lane];
        float x3 = xs[i4 * 4 + 3][lane];
        #pragma unroll
        for (int cc = 0; cc < 32; ++cc) {
            float4 wv = *reinterpret_cast<const float4*>(
                &w_in[(cg * 32 + cc) * C_INc + i4 * 4]);
            acc[cc] += wv.x * x0 + wv.y * x1 + wv.z * x2 + wv.w * x3;
        }
    }

    float s1 = 0.f, s2 = 0.f;
    #pragma unroll
    for (int cc = 0; cc < 32; ++cc) { s1 += acc[cc]; s2 += acc[cc] * acc[cc]; }
    __shared__ float r1[4][64], r2[4][64];
    r1[cg][lane] = s1; r2[cg][lane] = s2;
    __syncthreads();
    float m   = (r1[0][lane] + r1[1][lane] + r1[2][lane] + r1[3][lane]) * (1.f / C_Hc);
    float ex2 = (r2[0][lane] + r2[1][lane] + r2[2][lane] + r2[3][lane]) * (1.f / C_Hc);
    float rs  = rsqrtf(ex2 - m * m + EPSV);

    long long tbase = ((long long)((b << 14) + base + lane) << 7) + cg * 32;
    #pragma unroll
    for (int cc = 0; cc < 32; cc += 4) {
        int c0 = cg * 32 + cc;
        float4 g4 = *reinterpret_cast<const float4*>(&lng[c0]);
        float4 b4 = *reinterpret_cast<const float4*>(&lnb[c0]);
        float4 y;
        y.x = (acc[cc + 0] - m) * rs * g4.x + b4.x;
        y.y = (acc[cc + 1] - m) * rs * g4.y + b4.y;
        y.z = (acc[cc + 2] - m) * rs * g4.z + b4.z;
        y.w = (acc[cc + 3] - m) * rs * g4.w + b4.w;
        *reinterpret_cast<uint*>(&fT[tbase + cc])     = pack2(y.x, y.y);
        *reinterpret_cast<uint*>(&fT[tbase + cc + 2]) = pack2(y.z, y.w);
        if (!simg)
            *reinterpret_cast<float4*>(&featrT[tbase + cc]) = y;
    }
}

// ---------------------------------------------------------------------------
// conv3x3 + ReLU.  Block = half-row (64 px), 256 threads (4 waves), wave tile
// 32co x 64px.  Only the feat halo tile lives in LDS (one barrier total);
// weight A-fragments are read directly from L2-resident chunk-major wA.
// ---------------------------------------------------------------------------
__global__ __launch_bounds__(BLK, 3) void k_conv3(
    const ushort* __restrict__ fTr, const ushort* __restrict__ fTe,
    const ushort* __restrict__ wA,
    ushort* __restrict__ hTr, ushort* __restrict__ hTe)
{
    int bid = blockIdx.x;           // 2s * 2b * 128 rows * 2 halves = 1024
    int ph = bid & 1, h0 = (bid >> 1) & 127, b = (bid >> 8) & 1, s = bid >> 9;
    int w0 = ph << 6;
    const ushort* fT = s ? fTe : fTr;
    ushort* hT = s ? hTe : hTr;
    int tid = threadIdx.x, lane = tid & 63, wv = tid >> 6;
    int lpx = lane & 15, lk = lane >> 4;
    int co0 = wv * 32;

    __shared__ ushort ft[16 * 198 * 8];     // [chunk][row*66+col][8]  (50,688 B)

    const long long ibase = (long long)(b << 14);

    // stage feat rows h0-1..h0+1, cols w0-1..w0+64 (lds col 0..65)
    for (int i = tid; i < 16 * 198; i += BLK) {
        int chunk = i / 198;
        int rem = i - chunk * 198;
        int row = rem / 66, col = rem - row * 66;
        int gh = h0 + row - 1, gw = w0 + col - 1;
        uint4 v = make_uint4(0, 0, 0, 0);
        if ((unsigned)gh < 128u && (unsigned)gw < 128u)
            v = *reinterpret_cast<const uint4*>(
                &fT[((ibase + (gh << 7) + gw) << 7) + (chunk << 3)]);
        *reinterpret_cast<uint4*>(&ft[i << 3]) = v;
    }
    __syncthreads();

    f32x4 acc[2][4];
    #pragma unroll
    for (int f = 0; f < 2; ++f)
        #pragma unroll
        for (int p = 0; p < 4; ++p) acc[f][p] = f32x4{0.f, 0.f, 0.f, 0.f};

    for (int tap = 0; tap < 9; ++tap) {
        int ki = tap / 3, kj = tap - ki * 3;
        const ushort* wtp = &wA[tap << 14];
        short8 a[2][4];
        #pragma unroll
        for (int f = 0; f < 2; ++f) {
            int co = co0 + f * 16 + lpx;
            #pragma unroll
            for (int q = 0; q < 4; ++q)
                a[f][q] = *reinterpret_cast<const short8*>(
                    &wtp[(((q * 4 + lk) << 7) + co) << 3]);
        }
        #pragma unroll
        for (int p = 0; p < 4; ++p) {
            int col = p * 16 + lpx + kj;           // 0..65
            short8 bq[4];
            #pragma unroll
            for (int q = 0; q < 4; ++q)
                bq[q] = *reinterpret_cast<const short8*>(
                    &ft[((q * 4 + lk) * 198 + ki * 66 + col) << 3]);
            #pragma unroll
            for (int f = 0; f < 2; ++f)
                #pragma unroll
                for (int q = 0; q < 4; ++q)
                    acc[f][p] = __builtin_amdgcn_mfma_f32_16x16x32_bf16(
                        a[f][q], bq[q], acc[f][p], 0, 0, 0);
        }
    }

    long long obase = (ibase + ((long long)h0 << 7)) << 7;
    #pragma unroll
    for (int f = 0; f < 2; ++f)
        #pragma unroll
        for (int p = 0; p < 4; ++p) {
            int c  = co0 + f * 16 + (lk << 2);
            int px = w0 + p * 16 + lpx;
            float v0 = fmaxf(acc[f][p][0], 0.f), v1 = fmaxf(acc[f][p][1], 0.f);
            float v2 = fmaxf(acc[f][p][2], 0.f), v3 = fmaxf(acc[f][p][3], 0.f);
            ushort* dst = &hT[obase + ((long long)px << 7) + c];
            *reinterpret_cast<uint*>(&dst[0]) = pack2(v0, v1);
            *reinterpret_cast<uint*>(&dst[2]) = pack2(v2, v3);
        }
}

// ---------------------------------------------------------------------------
// Fused dynamic-filter.  Block = half-row (64 px), 256 threads (4 waves),
// wave tile 32co x 64px.  NO LDS, NO barriers: weight A-fragments stream
// straight from L2-resident chunk-major w2b; h B-fragments persistent in
// registers; taps software-pipeline freely.  Output enh bf16 NHWC.
// ---------------------------------------------------------------------------
__global__ __launch_bounds__(BLK, 3) void k_dfapply(
    const ushort* __restrict__ hTr, const ushort* __restrict__ hTe,
    const ushort* __restrict__ fTr, const ushort* __restrict__ fTe,
    const ushort* __restrict__ w2b,
    ushort* __restrict__ enhr, ushort* __restrict__ enhe)
{
    int bid = blockIdx.x;           // 2s * 2b * 128 rows * 2 halves = 1024
    int ph = bid & 1, h0 = (bid >> 1) & 127, b = (bid >> 8) & 1, s = bid >> 9;
    const ushort* hT = s ? hTe : hTr;
    const ushort* fT = s ? fTe : fTr;
    ushort* enh = s ? enhe : enhr;
    int tid = threadIdx.x, lane = tid & 63, wv = tid >> 6;
    int lpx = lane & 15, lk = lane >> 4;
    int co0 = wv * 32, px0 = ph << 6;

    const long long ibase = (long long)(b << 14);
    const long long rowbase = (ibase + ((long long)h0 << 7)) << 7;

    // persistent B fragments (h tile, 64px x 128ci) from global (L2)
    short8 bq[4][4];
    #pragma unroll
    for (int p = 0; p < 4; ++p) {
        int px = px0 + p * 16 + lpx;
        #pragma unroll
        for (int q = 0; q < 4; ++q)
            bq[p][q] = *reinterpret_cast<const short8*>(
                &hT[rowbase + ((long long)px << 7) + ((q * 4 + lk) << 3)]);
    }

    f32x4 osum[2][4];
    #pragma unroll
    for (int f = 0; f < 2; ++f)
        #pragma unroll
        for (int p = 0; p < 4; ++p) osum[f][p] = f32x4{0.f, 0.f, 0.f, 0.f};

    for (int k = 0; k < 25; ++k) {
        int k5 = k / 5;
        int dh = k5 - 2, dw = k - k5 * 5 - 2;
        int gh = h0 + dh;
        bool rowok = (unsigned)gh < 128u;
        const ushort* fprow = fT + ((ibase + ((long long)gh << 7)) << 7);
        const ushort* wkp = &w2b[k << 14];

        uint2 featv[4][2];
        #pragma unroll
        for (int p = 0; p < 4; ++p) {
            int gw = px0 + p * 16 + lpx + dw;
            bool ok = rowok && ((unsigned)gw < 128u);
            #pragma unroll
            for (int f = 0; f < 2; ++f) {
                uint2 v = make_uint2(0, 0);
                if (ok) v = *reinterpret_cast<const uint2*>(
                    &fprow[((long long)gw << 7) + co0 + f * 16 + (lk << 2)]);
                featv[p][f] = v;
            }
        }

        #pragma unroll
        for (int f = 0; f < 2; ++f) {
            int co = co0 + f * 16 + lpx;
            short8 a[4];
            #pragma unroll
            for (int q = 0; q < 4; ++q)
                a[q] = *reinterpret_cast<const short8*>(
                    &wkp[(((q * 4 + lk) << 7) + co) << 3]);
            __builtin_amdgcn_s_setprio(1);
            #pragma unroll
            for (int p = 0; p < 4; ++p) {
                f32x4 fac = f32x4{0.f, 0.f, 0.f, 0.f};
                #pragma unroll
                for (int q = 0; q < 4; ++q)
                    fac = __builtin_amdgcn_mfma_f32_16x16x32_bf16(
                        a[q], bq[p][q], fac, 0, 0, 0);
                uint2 fv = featv[p][f];
                osum[f][p][0] += fac[0] * bf2f((ushort)(fv.x & 0xffff));
                osum[f][p][1] += fac[1] * bf2f((ushort)(fv.x >> 16));
                osum[f][p][2] += fac[2] * bf2f((ushort)(fv.y & 0xffff));
                osum[f][p][3] += fac[3] * bf2f((ushort)(fv.y >> 16));
            }
            __builtin_amdgcn_s_setprio(0);
        }
    }

    // store enh NHWC bf16
    #pragma unroll
    for (int f = 0; f < 2; ++f)
        #pragma unroll
        for (int p = 0; p < 4; ++p) {
            int c  = co0 + f * 16 + (lk << 2);
            int px = px0 + p * 16 + lpx;
            uint2 o;
            o.x = pack2(osum[f][p][0], osum[f][p][1]);
            o.y = pack2(osum[f][p][2], osum[f][p][3]);
            *reinterpret_cast<uint2*>(&enh[rowbase + ((long long)px << 7) + c]) = o;
        }
}

// ---------------------------------------------------------------------------
// Tail: sp = w_sp @ enh_e (bf16 MFMA) -> sigmoid gate -> + fp32 feat residual
// -> LN (fp32 math) -> out conv as bf16 MFMA (xn rounded to bf16 at GEMM
// input only).  Block = 64 px, 256 threads (4 waves).  No LDS reuse.
// ---------------------------------------------------------------------------
__global__ __launch_bounds__(BLK, 2) void k_final(
    const ushort* __restrict__ enhr, const ushort* __restrict__ enhe,
    const float* __restrict__ featrT,
    const ushort* __restrict__ wspb, const ushort* __restrict__ woutb,
    const float* __restrict__ lng, const float* __restrict__ lnb,
    float* __restrict__ out)
{
    int bid = blockIdx.x;            // Bb * 256
    int b = bid >> 8;
    int px0g = (bid & 255) * 64;     // linear pixel base
    int tid = threadIdx.x, lane = tid & 63, wv = tid >> 6;
    int lpx = lane & 15, lk = lane >> 4;

    __shared__ ushort es[16 * 64 * 8];     // enh_e chunk-major (16 KB)
    __shared__ ushort xnb[16 * 64 * 8];    // normalized fused bf16 (16 KB)
    __shared__ float p1[4][64], p2[4][64];

    const long long ebase = ((long long)((b << 14) + px0g)) << 7;

    #pragma unroll
    for (int t = 0; t < 4; ++t) {
        int j = tid + (t << 8);
        int chunk = j >> 6, px = j & 63;
        *reinterpret_cast<uint4*>(&es[j << 3]) =
            *reinterpret_cast<const uint4*>(
                &enhe[ebase + ((long long)px << 7) + (chunk << 3)]);
    }
    __syncthreads();

    // sp GEMM: wave-tile 32co x 64px (co0 = wv*32); A-frags direct from global
    int co0 = wv * 32;
    f32x4 sp[2][4];
    #pragma unroll
    for (int f = 0; f < 2; ++f)
        #pragma unroll
        for (int p = 0; p < 4; ++p) sp[f][p] = f32x4{0.f, 0.f, 0.f, 0.f};
    #pragma unroll
    for (int q = 0; q < 4; ++q) {
        short8 a[2], bb[4];
        #pragma unroll
        for (int f = 0; f < 2; ++f)
            a[f] = *reinterpret_cast<const short8*>(
                &wspb[((((q * 4 + lk) << 7) + co0 + f * 16 + lpx)) << 3]);
        #pragma unroll
        for (int p = 0; p < 4; ++p)
            bb[p] = *reinterpret_cast<const short8*>(
                &es[((((q * 4 + lk) << 6) + p * 16 + lpx)) << 3]);
        #pragma unroll
        for (int f = 0; f < 2; ++f)
            #pragma unroll
            for (int p = 0; p < 4; ++p)
                sp[f][p] = __builtin_amdgcn_mfma_f32_16x16x32_bf16(
                    a[f], bb[p], sp[f][p], 0, 0, 0);
    }

    // gate + fuse (fp32 residual) + LN partials
    float fu[2][4][4];
    float s1[4] = {0.f, 0.f, 0.f, 0.f}, s2[4] = {0.f, 0.f, 0.f, 0.f};
    #pragma unroll
    for (int f = 0; f < 2; ++f) {
        int c4 = co0 + f * 16 + (lk << 2);
        #pragma unroll
        for (int p = 0; p < 4; ++p) {
            int px = p * 16 + lpx;
            long long poff = ebase + ((long long)px << 7) + c4;
            uint2 re2 = *reinterpret_cast<const uint2*>(&enhr[poff]);
            float4 rf4 = *reinterpret_cast<const float4*>(&featrT[poff]);
            float re[4] = { bf2f((ushort)(re2.x & 0xffff)), bf2f((ushort)(re2.x >> 16)),
                            bf2f((ushort)(re2.y & 0xffff)), bf2f((ushort)(re2.y >> 16)) };
            float rf[4] = { rf4.x, rf4.y, rf4.z, rf4.w };
            #pragma unroll
            for (int r = 0; r < 4; ++r) {
                float sg = 1.f / (1.f + __expf(-sp[f][p][r]));
                float v = re[r] * (1.f + sg) + rf[r];
                fu[f][p][r] = v;
                s1[p] += v; s2[p] += v * v;
            }
        }
    }
    #pragma unroll
    for (int p = 0; p < 4; ++p) {
        s1[p] += __shfl_xor(s1[p], 16); s1[p] += __shfl_xor(s1[p], 32);
        s2[p] += __shfl_xor(s2[p], 16); s2[p] += __shfl_xor(s2[p], 32);
    }
    if (lk == 0) {
        #pragma unroll
        for (int p = 0; p < 4; ++p) {
            p1[wv][p * 16 + lpx] = s1[p];
            p2[wv][p * 16 + lpx] = s2[p];
        }
    }
    __syncthreads();

    float mm[4], rs[4];
    #pragma unroll
    for (int p = 0; p < 4; ++p) {
        int px = p * 16 + lpx;
        float m   = (p1[0][px] + p1[1][px] + p1[2][px] + p1[3][px]) * (1.f / 128.f);
        float ex2 = (p2[0][px] + p2[1][px] + p2[2][px] + p2[3][px]) * (1.f / 128.f);
        mm[p] = m;
        rs[p] = rsqrtf(ex2 - m * m + EPSV);
    }

    // normalized fused -> xnb bf16 chunk-major
    #pragma unroll
    for (int f = 0; f < 2; ++f) {
        int c4 = co0 + f * 16 + (lk << 2);
        float4 g = *reinterpret_cast<const float4*>(&lng[c4]);
        float4 bta = *reinterpret_cast<const float4*>(&lnb[c4]);
        int chunk = c4 >> 3, off = c4 & 7;
        #pragma unroll
        for (int p = 0; p < 4; ++p) {
            int px = p * 16 + lpx;
            float y0 = (fu[f][p][0] - mm[p]) * rs[p] * g.x + bta.x;
            float y1 = (fu[f][p][1] - mm[p]) * rs[p] * g.y + bta.y;
            float y2 = (fu[f][p][2] - mm[p]) * rs[p] * g.z + bta.z;
            float y3 = (fu[f][p][3] - mm[p]) * rs[p] * g.w + bta.w;
            uint2 o; o.x = pack2(y0, y1); o.y = pack2(y2, y3);
            *reinterpret_cast<uint2*>(&xnb[(((chunk << 6) + px) << 3) + off]) = o;
        }
    }
    __syncthreads();

    // out GEMM (bf16 MFMA): 64co x 64px; wave-tile 16co x 64px
    int co0o = wv * 16;
    f32x4 oa[4];
    #pragma unroll
    for (int p = 0; p < 4; ++p) oa[p] = f32x4{0.f, 0.f, 0.f, 0.f};
    #pragma unroll
    for (int q = 0; q < 4; ++q) {
        short8 a = *reinterpret_cast<const short8*>(
            &woutb[((((q * 4 + lk) << 6) + co0o + lpx)) << 3]);
        #pragma unroll
        for (int p = 0; p < 4; ++p) {
            short8 bb = *reinterpret_cast<const short8*>(
                &xnb[((((q * 4 + lk) << 6) + p * 16 + lpx)) << 3]);
            oa[p] = __builtin_amdgcn_mfma_f32_16x16x32_bf16(a, bb, oa[p], 0, 0, 0);
        }
    }

    // store fp32 NCHW
    #pragma unroll
    for (int p = 0; p < 4; ++p) {
        int px = px0g + p * 16 + lpx;
        #pragma unroll
        for (int r = 0; r < 4; ++r) {
            int c = co0o + (lk << 2) + r;
            out[((long long)(b * C_INc + c) << 14) + px] = oa[p][r];
        }
    }
}

// ---------------------------------------------------------------------------
extern "C" void kernel_launch(void* const* d_in, const int* in_sizes, int n_in,
                              void* d_out, int out_size, void* d_ws, size_t ws_size,
                              hipStream_t stream)
{
    const float* rgb  = (const float*)d_in[0];
    const float* evt  = (const float*)d_in[1];
    const float* w_in = (const float*)d_in[2];
    const float* lng  = (const float*)d_in[3];
    const float* lnb  = (const float*)d_in[4];
    const float* w1   = (const float*)d_in[5];
    const float* w2   = (const float*)d_in[6];
    const float* wsp  = (const float*)d_in[7];
    const float* wout = (const float*)d_in[8];
    float* out = (float*)d_out;

    float* ws = (float*)d_ws;
    ushort* fTr    = (ushort*)(ws);
    ushort* fTe    = (ushort*)(ws + 2097152);
    ushort* hTr    = (ushort*)(ws + 4194304);
    ushort* hTe    = (ushort*)(ws + 6291456);
    ushort* enhr   = (ushort*)(ws + 8388608);
    ushort* enhe   = (ushort*)(ws + 10485760);
    float*  featrT = (float*)(ws + 12582912);   // 4,194,304 f (fp32 NHWC, rgb)
    ushort* wA     = (ushort*)(ws + 16777216);  // 147456 bf16
    ushort* w2b    = (ushort*)(ws + 16850944);  // 409600 bf16
    ushort* wspb   = (ushort*)(ws + 17055744);  // 16384 bf16
    ushort* woutb  = (ushort*)(ws + 17063936);  // 8192 bf16

    k_prep<<<2272, BLK, 0, stream>>>(w1, w2, wsp, wout, wA, w2b, wspb, woutb);
    k_in_ln<<<2 * Bb * 256, BLK, 0, stream>>>(rgb, evt, w_in, lng, lnb,
                                              fTr, fTe, featrT);
    k_conv3<<<1024, BLK, 0, stream>>>(fTr, fTe, wA, hTr, hTe);
    k_dfapply<<<1024, BLK, 0, stream>>>(hTr, hTe, fTr, fTe, w2b, enhr, enhe);
    k_final<<<Bb * 256, BLK, 0, stream>>>(enhr, enhe, featrT, wspb, woutb,
                                          lng, lnb, out);
}

// Round 8
// 257.591 us; speedup vs baseline: 18.0484x; 1.1555x over previous
//
#include <hip/hip_runtime.h>
#include <math.h>

#define BLK 256

typedef unsigned short ushort;
typedef unsigned int uint;
typedef __attribute__((ext_vector_type(8))) short short8;
typedef __attribute__((ext_vector_type(4))) float f32x4;

constexpr int C_Hc = 128;
constexpr int C_INc = 64;
constexpr int Hh = 128;
constexpr int Ww = 128;
constexpr int HWc = Hh * Ww;   // 16384
constexpr int Bb = 2;
constexpr float EPSV = 1e-5f;

__device__ __forceinline__ float bf2f(ushort u) {
    union { uint u32; float f; } v; v.u32 = (uint)u << 16; return v.f;
}
__device__ __forceinline__ ushort f2bf(float x) {
    union { float f; uint u; } v; v.f = x;
    uint r = (v.u + 0x7FFFu + ((v.u >> 16) & 1u)) >> 16;
    return (ushort)r;
}
__device__ __forceinline__ uint pack2(float a, float b) {
    return (uint)f2bf(a) | ((uint)f2bf(b) << 16);
}
__device__ __forceinline__ void gload16(const ushort* g, ushort* l) {
    __builtin_amdgcn_global_load_lds(
        (const __attribute__((address_space(1))) void*)g,
        (__attribute__((address_space(3))) void*)l, 16, 0, 0);
}

// ---------------------------------------------------------------------------
// Weight prep (chunk-major bf16: [chunk][co][8], chunk = ci/8):
//   wA[tap][16][128][8], w2b[k][16][128][8], wspb[16][128][8],
//   woutb/woutlo[16][64][8] (Dekker hi/lo split of w_out)
// ---------------------------------------------------------------------------
__global__ __launch_bounds__(BLK) void k_prep(
    const float* __restrict__ w1, const float* __restrict__ w2,
    const float* __restrict__ wsp, const float* __restrict__ wout,
    ushort* __restrict__ wA, ushort* __restrict__ w2b,
    ushort* __restrict__ wspb, ushort* __restrict__ woutb,
    ushort* __restrict__ woutlo)
{
    int idx = blockIdx.x * BLK + threadIdx.x;
    if (idx < 147456) {                       // wA: 9 * 16384
        int tap = idx >> 14, r = idx & 16383;
        int chunk = r >> 10, co = (r >> 3) & 127, e = r & 7;
        int ci = chunk * 8 + e;
        wA[idx] = f2bf(w1[(co * 128 + ci) * 9 + tap]);
    } else if (idx < 557056) {                // w2b: 25 * 16384
        int o = idx - 147456;
        int k = o >> 14, r = o & 16383;
        int chunk = r >> 10, co = (r >> 3) & 127, e = r & 7;
        int ci = chunk * 8 + e;
        w2b[o] = f2bf(w2[(co * 25 + k) * 128 + ci]);
    } else if (idx < 573440) {                // wspb: 16384
        int o = idx - 557056;
        int chunk = o >> 10, co = (o >> 3) & 127, e = o & 7;
        wspb[o] = f2bf(wsp[co * 128 + chunk * 8 + e]);
    } else if (idx < 581632) {                // woutb + woutlo: 8192
        int o = idx - 573440;
        int chunk = o >> 9, co = (o >> 3) & 63, e = o & 7;
        float w = wout[co * 128 + chunk * 8 + e];
        ushort hi = f2bf(w);
        woutb[o]  = hi;
        woutlo[o] = f2bf(w - bf2f(hi));
    }
}

// ---------------------------------------------------------------------------
// conv1x1(w_in) + LayerNorm; writes featT bf16 NHWC (both streams) and
// featrT fp32 NHWC (rgb only, fp32 residual for the tail).
// ---------------------------------------------------------------------------
__global__ __launch_bounds__(BLK) void k_in_ln(
    const float* __restrict__ xr, const float* __restrict__ xe,
    const float* __restrict__ w_in, const float* __restrict__ lng,
    const float* __restrict__ lnb,
    ushort* __restrict__ fTr, ushort* __restrict__ fTe,
    float* __restrict__ featrT)
{
    int bid  = blockIdx.x;          // 2 * Bb * 256
    int simg = bid >> 9;
    int rem  = bid & 511;
    int b    = rem >> 8;
    int base = (rem & 255) * 64;
    const float* x = simg ? xe : xr;
    ushort* fT = simg ? fTe : fTr;
    int lane = threadIdx.x & 63;
    int cg   = threadIdx.x >> 6;

    __shared__ float xs[C_INc][64];
    #pragma unroll
    for (int r = 0; r < 16; ++r) {
        int i = cg * 16 + r;
        xs[i][lane] = x[(b * C_INc + i) * HWc + base + lane];
    }
    __syncthreads();

    float acc[32];
    #pragma unroll
    for (int cc = 0; cc < 32; ++cc) acc[cc] = 0.f;

    for (int i4 = 0; i4 < 16; ++i4) {
        float x0 = xs[i4 * 4 + 0][lane];
        float x1 = xs[i4 * 4 + 1][lane];
        float x2 = xs[i4 * 4 + 2][lane];
        float x3 = xs[i4 * 4 + 3][lane];
        #pragma unroll
        for (int cc = 0; cc < 32; ++cc) {
            float4 wv = *reinterpret_cast<const float4*>(
                &w_in[(cg * 32 + cc) * C_INc + i4 * 4]);
            acc[cc] += wv.x * x0 + wv.y * x1 + wv.z * x2 + wv.w * x3;
        }
    }

    float s1 = 0.f, s2 = 0.f;
    #pragma unroll
    for (int cc = 0; cc < 32; ++cc) { s1 += acc[cc]; s2 += acc[cc] * acc[cc]; }
    __shared__ float r1[4][64], r2[4][64];
    r1[cg][lane] = s1; r2[cg][lane] = s2;
    __syncthreads();
    float m   = (r1[0][lane] + r1[1][lane] + r1[2][lane] + r1[3][lane]) * (1.f / C_Hc);
    float ex2 = (r2[0][lane] + r2[1][lane] + r2[2][lane] + r2[3][lane]) * (1.f / C_Hc);
    float rs  = rsqrtf(ex2 - m * m + EPSV);

    long long tbase = ((long long)((b << 14) + base + lane) << 7) + cg * 32;
    #pragma unroll
    for (int cc = 0; cc < 32; cc += 4) {
        int c0 = cg * 32 + cc;
        float4 g4 = *reinterpret_cast<const float4*>(&lng[c0]);
        float4 b4 = *reinterpret_cast<const float4*>(&lnb[c0]);
        float4 y;
        y.x = (acc[cc + 0] - m) * rs * g4.x + b4.x;
        y.y = (acc[cc + 1] - m) * rs * g4.y + b4.y;
        y.z = (acc[cc + 2] - m) * rs * g4.z + b4.z;
        y.w = (acc[cc + 3] - m) * rs * g4.w + b4.w;
        *reinterpret_cast<uint*>(&fT[tbase + cc])     = pack2(y.x, y.y);
        *reinterpret_cast<uint*>(&fT[tbase + cc + 2]) = pack2(y.z, y.w);
        if (!simg)
            *reinterpret_cast<float4*>(&featrT[tbase + cc]) = y;
    }
}

// ---------------------------------------------------------------------------
// conv3x3 + ReLU (exact Round-6 version, passed).  Block = half-row (64 px),
// 256 threads (4 waves), wave tile 32co x 64px.  Halo in LDS (one barrier);
// weight A-fragments from L2-resident chunk-major wA.
// ---------------------------------------------------------------------------
__global__ __launch_bounds__(BLK, 3) void k_conv3(
    const ushort* __restrict__ fTr, const ushort* __restrict__ fTe,
    const ushort* __restrict__ wA,
    ushort* __restrict__ hTr, ushort* __restrict__ hTe)
{
    int bid = blockIdx.x;           // 2s * 2b * 128 rows * 2 halves = 1024
    int ph = bid & 1, h0 = (bid >> 1) & 127, b = (bid >> 8) & 1, s = bid >> 9;
    int w0 = ph << 6;
    const ushort* fT = s ? fTe : fTr;
    ushort* hT = s ? hTe : hTr;
    int tid = threadIdx.x, lane = tid & 63, wv = tid >> 6;
    int lpx = lane & 15, lk = lane >> 4;
    int co0 = wv * 32;

    __shared__ ushort ft[16 * 198 * 8];     // [chunk][row*66+col][8]  (50,688 B)

    const long long ibase = (long long)(b << 14);

    for (int i = tid; i < 16 * 198; i += BLK) {
        int chunk = i / 198;
        int rem = i - chunk * 198;
        int row = rem / 66, col = rem - row * 66;
        int gh = h0 + row - 1, gw = w0 + col - 1;
        uint4 v = make_uint4(0, 0, 0, 0);
        if ((unsigned)gh < 128u && (unsigned)gw < 128u)
            v = *reinterpret_cast<const uint4*>(
                &fT[((ibase + (gh << 7) + gw) << 7) + (chunk << 3)]);
        *reinterpret_cast<uint4*>(&ft[i << 3]) = v;
    }
    __syncthreads();

    f32x4 acc[2][4];
    #pragma unroll
    for (int f = 0; f < 2; ++f)
        #pragma unroll
        for (int p = 0; p < 4; ++p) acc[f][p] = f32x4{0.f, 0.f, 0.f, 0.f};

    for (int tap = 0; tap < 9; ++tap) {
        int ki = tap / 3, kj = tap - ki * 3;
        const ushort* wtp = &wA[tap << 14];
        short8 a[2][4];
        #pragma unroll
        for (int f = 0; f < 2; ++f) {
            int co = co0 + f * 16 + lpx;
            #pragma unroll
            for (int q = 0; q < 4; ++q)
                a[f][q] = *reinterpret_cast<const short8*>(
                    &wtp[(((q * 4 + lk) << 7) + co) << 3]);
        }
        #pragma unroll
        for (int p = 0; p < 4; ++p) {
            int col = p * 16 + lpx + kj;           // 0..65
            short8 bq[4];
            #pragma unroll
            for (int q = 0; q < 4; ++q)
                bq[q] = *reinterpret_cast<const short8*>(
                    &ft[((q * 4 + lk) * 198 + ki * 66 + col) << 3]);
            #pragma unroll
            for (int f = 0; f < 2; ++f)
                #pragma unroll
                for (int q = 0; q < 4; ++q)
                    acc[f][p] = __builtin_amdgcn_mfma_f32_16x16x32_bf16(
                        a[f][q], bq[q], acc[f][p], 0, 0, 0);
        }
    }

    long long obase = (ibase + ((long long)h0 << 7)) << 7;
    #pragma unroll
    for (int f = 0; f < 2; ++f)
        #pragma unroll
        for (int p = 0; p < 4; ++p) {
            int c  = co0 + f * 16 + (lk << 2);
            int px = w0 + p * 16 + lpx;
            float v0 = fmaxf(acc[f][p][0], 0.f), v1 = fmaxf(acc[f][p][1], 0.f);
            float v2 = fmaxf(acc[f][p][2], 0.f), v3 = fmaxf(acc[f][p][3], 0.f);
            ushort* dst = &hT[obase + ((long long)px << 7) + c];
            *reinterpret_cast<uint*>(&dst[0]) = pack2(v0, v1);
            *reinterpret_cast<uint*>(&dst[2]) = pack2(v2, v3);
        }
}

// ---------------------------------------------------------------------------
// Fused dynamic-filter (exact Round-5 version, passed twice; 120 us).
// Block = 1 row (128co x 128px), 256 threads (4 waves), wave tile 64co x 64px.
// Chunk-major LDS; w2b[k] DMA double-buffered; 1 barrier/tap.
// ---------------------------------------------------------------------------
__global__ __launch_bounds__(BLK, 2) void k_dfapply(
    const ushort* __restrict__ hTr, const ushort* __restrict__ hTe,
    const ushort* __restrict__ fTr, const ushort* __restrict__ fTe,
    const ushort* __restrict__ w2b,
    ushort* __restrict__ enhr, ushort* __restrict__ enhe)
{
    int bid = blockIdx.x;           // 2s * 2b * 128 rows
    int s = bid >> 8, b = (bid >> 7) & 1, h0 = bid & 127;
    const ushort* hT = s ? hTe : hTr;
    const ushort* fT = s ? fTe : fTr;
    ushort* enh = s ? enhe : enhr;
    int tid = threadIdx.x, lane = tid & 63, wv = tid >> 6;
    int lpx = lane & 15, lk = lane >> 4;
    int co0 = (wv & 1) * 64, px0 = (wv >> 1) * 64;

    __shared__ ushort wk[2][16 * 128 * 8];       // 2 x 32 KB chunk-major

    const long long ibase = (long long)(b << 14);
    const long long rowbase = (ibase + ((long long)h0 << 7)) << 7;

    // persistent B fragments (h tile) from global (L2)
    short8 bq[4][4];
    #pragma unroll
    for (int p = 0; p < 4; ++p) {
        int px = px0 + p * 16 + lpx;
        #pragma unroll
        for (int q = 0; q < 4; ++q)
            bq[p][q] = *reinterpret_cast<const short8*>(
                &hT[rowbase + ((long long)px << 7) + ((q * 4 + lk) << 3)]);
    }

    // DMA-stage wk[0] for k=0 (chunk-major -> fully contiguous)
    #pragma unroll
    for (int t = 0; t < 8; ++t) {
        int j = tid + (t << 8);
        gload16(&w2b[j << 3], &wk[0][j << 3]);
    }
    __syncthreads();

    f32x4 osum[4][4];
    #pragma unroll
    for (int f = 0; f < 4; ++f)
        #pragma unroll
        for (int p = 0; p < 4; ++p) osum[f][p] = f32x4{0.f, 0.f, 0.f, 0.f};

    for (int k = 0; k < 25; ++k) {
        int cur = k & 1;
        if (k < 24) {   // DMA prefetch k+1 into other buffer
            const ushort* srcb = &w2b[(k + 1) << 14];
            #pragma unroll
            for (int t = 0; t < 8; ++t) {
                int j = tid + (t << 8);
                gload16(&srcb[j << 3], &wk[cur ^ 1][j << 3]);
            }
        }
        int k5 = k / 5;
        int dh = k5 - 2, dw = k - k5 * 5 - 2;
        int gh = h0 + dh;
        bool rowok = (unsigned)gh < 128u;
        const ushort* fprow = fT + ((ibase + ((long long)gh << 7)) << 7);

        uint2 featv[4][4];
        #pragma unroll
        for (int p = 0; p < 4; ++p) {
            int gw = px0 + p * 16 + lpx + dw;
            bool ok = rowok && ((unsigned)gw < 128u);
            #pragma unroll
            for (int f = 0; f < 4; ++f) {
                uint2 v = make_uint2(0, 0);
                if (ok) v = *reinterpret_cast<const uint2*>(
                    &fprow[((long long)gw << 7) + co0 + f * 16 + (lk << 2)]);
                featv[p][f] = v;
            }
        }

        #pragma unroll
        for (int f = 0; f < 4; ++f) {
            int co = co0 + f * 16 + lpx;
            short8 a[4];
            #pragma unroll
            for (int q = 0; q < 4; ++q)
                a[q] = *reinterpret_cast<const short8*>(
                    &wk[cur][(((q * 4 + lk) << 7) + co) << 3]);
            __builtin_amdgcn_s_setprio(1);
            #pragma unroll
            for (int p = 0; p < 4; ++p) {
                f32x4 fac = f32x4{0.f, 0.f, 0.f, 0.f};
                #pragma unroll
                for (int q = 0; q < 4; ++q)
                    fac = __builtin_amdgcn_mfma_f32_16x16x32_bf16(
                        a[q], bq[p][q], fac, 0, 0, 0);
                uint2 fv = featv[p][f];
                osum[f][p][0] += fac[0] * bf2f((ushort)(fv.x & 0xffff));
                osum[f][p][1] += fac[1] * bf2f((ushort)(fv.x >> 16));
                osum[f][p][2] += fac[2] * bf2f((ushort)(fv.y & 0xffff));
                osum[f][p][3] += fac[3] * bf2f((ushort)(fv.y >> 16));
            }
            __builtin_amdgcn_s_setprio(0);
        }
        __syncthreads();   // DMA k+1 landed; all reads of wk[cur] done
    }

    // store enh NHWC bf16
    #pragma unroll
    for (int f = 0; f < 4; ++f)
        #pragma unroll
        for (int p = 0; p < 4; ++p) {
            int c  = co0 + f * 16 + (lk << 2);
            int px = px0 + p * 16 + lpx;
            uint2 o;
            o.x = pack2(osum[f][p][0], osum[f][p][1]);
            o.y = pack2(osum[f][p][2], osum[f][p][3]);
            *reinterpret_cast<uint2*>(&enh[rowbase + ((long long)px << 7) + c]) = o;
        }
}

// ---------------------------------------------------------------------------
// Tail: sp = w_sp @ enh_e (bf16 MFMA) -> sigmoid gate -> + fp32 feat residual
// -> LN (fp32) -> out conv as 3-pass split-bf16 MFMA:
//   out = Wh@xh + Wh@xl + Wl@xh   (W and xn both Dekker-split to 2x bf16)
// Operand error ~2^-17 (fp32-equivalent).  Block = 64 px, 4 waves.
// ---------------------------------------------------------------------------
__global__ __launch_bounds__(BLK, 2) void k_final(
    const ushort* __restrict__ enhr, const ushort* __restrict__ enhe,
    const float* __restrict__ featrT,
    const ushort* __restrict__ wspb, const ushort* __restrict__ woutb,
    const ushort* __restrict__ woutlo,
    const float* __restrict__ lng, const float* __restrict__ lnb,
    float* __restrict__ out)
{
    int bid = blockIdx.x;            // Bb * 256
    int b = bid >> 8;
    int px0g = (bid & 255) * 64;     // linear pixel base
    int tid = threadIdx.x, lane = tid & 63, wv = tid >> 6;
    int lpx = lane & 15, lk = lane >> 4;

    __shared__ ushort es[16 * 64 * 8];     // enh_e chunk-major (16 KB)
    __shared__ ushort xnb[16 * 64 * 8];    // xn hi bf16 (16 KB)
    __shared__ ushort xlb[16 * 64 * 8];    // xn lo bf16 (16 KB)
    __shared__ float p1[4][64], p2[4][64];

    const long long ebase = ((long long)((b << 14) + px0g)) << 7;

    #pragma unroll
    for (int t = 0; t < 4; ++t) {
        int j = tid + (t << 8);
        int chunk = j >> 6, px = j & 63;
        *reinterpret_cast<uint4*>(&es[j << 3]) =
            *reinterpret_cast<const uint4*>(
                &enhe[ebase + ((long long)px << 7) + (chunk << 3)]);
    }
    __syncthreads();

    // sp GEMM: wave-tile 32co x 64px (co0 = wv*32); A-frags direct from global
    int co0 = wv * 32;
    f32x4 sp[2][4];
    #pragma unroll
    for (int f = 0; f < 2; ++f)
        #pragma unroll
        for (int p = 0; p < 4; ++p) sp[f][p] = f32x4{0.f, 0.f, 0.f, 0.f};
    #pragma unroll
    for (int q = 0; q < 4; ++q) {
        short8 a[2], bb[4];
        #pragma unroll
        for (int f = 0; f < 2; ++f)
            a[f] = *reinterpret_cast<const short8*>(
                &wspb[((((q * 4 + lk) << 7) + co0 + f * 16 + lpx)) << 3]);
        #pragma unroll
        for (int p = 0; p < 4; ++p)
            bb[p] = *reinterpret_cast<const short8*>(
                &es[((((q * 4 + lk) << 6) + p * 16 + lpx)) << 3]);
        #pragma unroll
        for (int f = 0; f < 2; ++f)
            #pragma unroll
            for (int p = 0; p < 4; ++p)
                sp[f][p] = __builtin_amdgcn_mfma_f32_16x16x32_bf16(
                    a[f], bb[p], sp[f][p], 0, 0, 0);
    }

    // gate + fuse (fp32 residual) + LN partials
    float fu[2][4][4];
    float s1[4] = {0.f, 0.f, 0.f, 0.f}, s2[4] = {0.f, 0.f, 0.f, 0.f};
    #pragma unroll
    for (int f = 0; f < 2; ++f) {
        int c4 = co0 + f * 16 + (lk << 2);
        #pragma unroll
        for (int p = 0; p < 4; ++p) {
            int px = p * 16 + lpx;
            long long poff = ebase + ((long long)px << 7) + c4;
            uint2 re2 = *reinterpret_cast<const uint2*>(&enhr[poff]);
            float4 rf4 = *reinterpret_cast<const float4*>(&featrT[poff]);
            float re[4] = { bf2f((ushort)(re2.x & 0xffff)), bf2f((ushort)(re2.x >> 16)),
                            bf2f((ushort)(re2.y & 0xffff)), bf2f((ushort)(re2.y >> 16)) };
            float rf[4] = { rf4.x, rf4.y, rf4.z, rf4.w };
            #pragma unroll
            for (int r = 0; r < 4; ++r) {
                float sg = 1.f / (1.f + __expf(-sp[f][p][r]));
                float v = re[r] * (1.f + sg) + rf[r];
                fu[f][p][r] = v;
                s1[p] += v; s2[p] += v * v;
            }
        }
    }
    #pragma unroll
    for (int p = 0; p < 4; ++p) {
        s1[p] += __shfl_xor(s1[p], 16); s1[p] += __shfl_xor(s1[p], 32);
        s2[p] += __shfl_xor(s2[p], 16); s2[p] += __shfl_xor(s2[p], 32);
    }
    if (lk == 0) {
        #pragma unroll
        for (int p = 0; p < 4; ++p) {
            p1[wv][p * 16 + lpx] = s1[p];
            p2[wv][p * 16 + lpx] = s2[p];
        }
    }
    __syncthreads();

    float mm[4], rs[4];
    #pragma unroll
    for (int p = 0; p < 4; ++p) {
        int px = p * 16 + lpx;
        float m   = (p1[0][px] + p1[1][px] + p1[2][px] + p1[3][px]) * (1.f / 128.f);
        float ex2 = (p2[0][px] + p2[1][px] + p2[2][px] + p2[3][px]) * (1.f / 128.f);
        mm[p] = m;
        rs[p] = rsqrtf(ex2 - m * m + EPSV);
    }

    // normalized fused -> xnb (hi) + xlb (lo), bf16 chunk-major (Dekker split)
    #pragma unroll
    for (int f = 0; f < 2; ++f) {
        int c4 = co0 + f * 16 + (lk << 2);
        float4 g = *reinterpret_cast<const float4*>(&lng[c4]);
        float4 bta = *reinterpret_cast<const float4*>(&lnb[c4]);
        int chunk = c4 >> 3, off = c4 & 7;
        #pragma unroll
        for (int p = 0; p < 4; ++p) {
            int px = p * 16 + lpx;
            float y0 = (fu[f][p][0] - mm[p]) * rs[p] * g.x + bta.x;
            float y1 = (fu[f][p][1] - mm[p]) * rs[p] * g.y + bta.y;
            float y2 = (fu[f][p][2] - mm[p]) * rs[p] * g.z + bta.z;
            float y3 = (fu[f][p][3] - mm[p]) * rs[p] * g.w + bta.w;
            ushort h0b = f2bf(y0), h1b = f2bf(y1), h2b = f2bf(y2), h3b = f2bf(y3);
            uint2 oh;
            oh.x = (uint)h0b | ((uint)h1b << 16);
            oh.y = (uint)h2b | ((uint)h3b << 16);
            *reinterpret_cast<uint2*>(&xnb[(((chunk << 6) + px) << 3) + off]) = oh;
            uint2 ol;
            ol.x = pack2(y0 - bf2f(h0b), y1 - bf2f(h1b));
            ol.y = pack2(y2 - bf2f(h2b), y3 - bf2f(h3b));
            *reinterpret_cast<uint2*>(&xlb[(((chunk << 6) + px) << 3) + off]) = ol;
        }
    }
    __syncthreads();

    // out GEMM: 3-pass split-bf16.  64co x 64px; wave-tile 16co x 64px.
    int co0o = wv * 16;
    f32x4 oa[4];
    #pragma unroll
    for (int p = 0; p < 4; ++p) oa[p] = f32x4{0.f, 0.f, 0.f, 0.f};
    #pragma unroll
    for (int q = 0; q < 4; ++q) {
        int widx = (((q * 4 + lk) << 6) + co0o + lpx) << 3;
        short8 ah = *reinterpret_cast<const short8*>(&woutb[widx]);
        short8 al = *reinterpret_cast<const short8*>(&woutlo[widx]);
        #pragma unroll
        for (int p = 0; p < 4; ++p) {
            int bidx = (((q * 4 + lk) << 6) + p * 16 + lpx) << 3;
            short8 bh = *reinterpret_cast<const short8*>(&xnb[bidx]);
            short8 bl = *reinterpret_cast<const short8*>(&xlb[bidx]);
            oa[p] = __builtin_amdgcn_mfma_f32_16x16x32_bf16(ah, bh, oa[p], 0, 0, 0);
            oa[p] = __builtin_amdgcn_mfma_f32_16x16x32_bf16(ah, bl, oa[p], 0, 0, 0);
            oa[p] = __builtin_amdgcn_mfma_f32_16x16x32_bf16(al, bh, oa[p], 0, 0, 0);
        }
    }

    // store fp32 NCHW
    #pragma unroll
    for (int p = 0; p < 4; ++p) {
        int px = px0g + p * 16 + lpx;
        #pragma unroll
        for (int r = 0; r < 4; ++r) {
            int c = co0o + (lk << 2) + r;
            out[((long long)(b * C_INc + c) << 14) + px] = oa[p][r];
        }
    }
}

// ---------------------------------------------------------------------------
extern "C" void kernel_launch(void* const* d_in, const int* in_sizes, int n_in,
                              void* d_out, int out_size, void* d_ws, size_t ws_size,
                              hipStream_t stream)
{
    const float* rgb  = (const float*)d_in[0];
    const float* evt  = (const float*)d_in[1];
    const float* w_in = (const float*)d_in[2];
    const float* lng  = (const float*)d_in[3];
    const float* lnb  = (const float*)d_in[4];
    const float* w1   = (const float*)d_in[5];
    const float* w2   = (const float*)d_in[6];
    const float* wsp  = (const float*)d_in[7];
    const float* wout = (const float*)d_in[8];
    float* out = (float*)d_out;

    float* ws = (float*)d_ws;
    ushort* fTr    = (ushort*)(ws);
    ushort* fTe    = (ushort*)(ws + 2097152);
    ushort* hTr    = (ushort*)(ws + 4194304);
    ushort* hTe    = (ushort*)(ws + 6291456);
    ushort* enhr   = (ushort*)(ws + 8388608);
    ushort* enhe   = (ushort*)(ws + 10485760);
    float*  featrT = (float*)(ws + 12582912);   // 4,194,304 f (fp32 NHWC, rgb)
    ushort* wA     = (ushort*)(ws + 16777216);  // 147456 bf16
    ushort* w2b    = (ushort*)(ws + 16850944);  // 409600 bf16
    ushort* wspb   = (ushort*)(ws + 17055744);  // 16384 bf16
    ushort* woutb  = (ushort*)(ws + 17063936);  // 8192 bf16
    ushort* woutlo = (ushort*)(ws + 17068032);  // 8192 bf16

    k_prep<<<2272, BLK, 0, stream>>>(w1, w2, wsp, wout, wA, w2b, wspb,
                                     woutb, woutlo);
    k_in_ln<<<2 * Bb * 256, BLK, 0, stream>>>(rgb, evt, w_in, lng, lnb,
                                              fTr, fTe, featrT);
    k_conv3<<<1024, BLK, 0, stream>>>(fTr, fTe, wA, hTr, hTe);
    k_dfapply<<<512, BLK, 0, stream>>>(hTr, hTe, fTr, fTe, w2b, enhr, enhe);
    k_final<<<Bb * 256, BLK, 0, stream>>>(enhr, enhe, featrT, wspb,
                                          woutb, woutlo, lng, lnb, out);
}